// Round 12
// baseline (184.443 us; speedup 1.0000x reference)
//
#include <hip/hip_runtime.h>

// ---------------------------------------------------------------------------
// WAM_13056700579937: out = softmax_ax1(softmax_ax2((X X^T) W^T)) @ X + X
// B=16, C=512, HW=4096. fp32 in/out; internal bf16 MFMA (16x16x32).
//
// Round 12: 2-deep LDS (32 KB, 3->5 blocks/CU) in gsym + gemms, counted
// vmcnt kept (never 0 in loop); non-temporal stores for out and xT.
// ---------------------------------------------------------------------------

typedef __attribute__((ext_vector_type(8))) short bf16x8;   // 8 bf16 = 4 VGPR
typedef __attribute__((ext_vector_type(4))) float f32x4;
typedef __attribute__((ext_vector_type(4))) unsigned int u32x4;

#define DEVINL __device__ __forceinline__
#define CFENCE() asm volatile("" ::: "memory")

DEVINL unsigned short f2bf(float f) {   // RNE float->bf16 (finite inputs)
  union { float f; unsigned int u; } c; c.f = f;
  unsigned int u = c.u;
  u += 0x7fffu + ((u >> 16) & 1u);
  return (unsigned short)(u >> 16);
}

DEVINL float bf2f(unsigned short h) {
  union { unsigned int u; float f; } c; c.u = ((unsigned int)h) << 16;
  return c.f;
}

DEVINL void gld_lds16(const unsigned short* g, unsigned short* l) {
  __builtin_amdgcn_global_load_lds(
      (const __attribute__((address_space(1))) unsigned int*)g,
      (__attribute__((address_space(3))) unsigned int*)l,
      16 /*bytes, literal*/, 0, 0);
}

template<int N> DEVINL void vm_wait() {
  if constexpr (N == 0)       asm volatile("s_waitcnt vmcnt(0)" ::: "memory");
  else if constexpr (N == 2)  asm volatile("s_waitcnt vmcnt(2)" ::: "memory");
  else if constexpr (N == 4)  asm volatile("s_waitcnt vmcnt(4)" ::: "memory");
  else if constexpr (N == 8)  asm volatile("s_waitcnt vmcnt(8)" ::: "memory");
  else static_assert(N < 0, "unsupported vmcnt");
}

DEVINL void sym_tile_decode(int t, int& tm, int& tn) {  // t in [0,10) -> upper 4x4
  if (t < 4)      { tm = 0; tn = t; }
  else if (t < 7) { tm = 1; tn = t - 3; }
  else if (t < 9) { tm = 2; tn = t - 5; }
  else            { tm = 3; tn = 3; }
}

// ---------------------------------------------------------------------------
// cvt fp32 -> bf16 (W only)
// ---------------------------------------------------------------------------
__global__ __launch_bounds__(256)
void cvt_kernel(const float* __restrict__ in, unsigned short* __restrict__ out, int n4) {
  int i = blockIdx.x * 256 + threadIdx.x;
  const int stride = gridDim.x * 256;
  for (; i < n4; i += stride) {
    float4 v = ((const float4*)in)[i];
    unsigned int lo = (unsigned int)f2bf(v.x) | ((unsigned int)f2bf(v.y) << 16);
    unsigned int hi = (unsigned int)f2bf(v.z) | ((unsigned int)f2bf(v.w) << 16);
    uint2 o; o.x = lo; o.y = hi;
    ((uint2*)out)[i] = o;
  }
}

// ---------------------------------------------------------------------------
// Fused convert + transpose (round-9 structure). Reads x fp32 ONCE.
// Phase 1: loads + cvt + vertical-pair pack -> LDS [c2][h] u32 (b128 writes).
// Barrier waits lgkmcnt(0) only; global stores all post-barrier.
// Phase 2: 4x b128 LDS reads + register 4x4 u32 transpose + 4x 16B NT stores.
// xT stores are NON-TEMPORAL (consumed ~100us later; don't pollute L2).
// ---------------------------------------------------------------------------
__global__ __launch_bounds__(256)
void fused_cvt_transpose(const float* __restrict__ x, unsigned short* __restrict__ x_bf,
                         unsigned short* __restrict__ xT) {
  __shared__ unsigned int T[2][32][68];   // 17408 B; 272 B rows, 16B-aligned
  const int tid = threadIdx.x;
  const int b  = blockIdx.y;
  const int hs = blockIdx.x & 31;         // 32 h-slots of 128
  const int ct = blockIdx.x >> 5;         // 8 c-tiles of 64
  const int h0 = hs * 128;
  const int hq = tid & 7;                 // 8 h-chunks of 8
  const int c2 = tid >> 3;                // 32 c-pairs

  uint4 pa[2], pb[2];
  long long rowA[2];
  #pragma unroll
  for (int hh = 0; hh < 2; ++hh) {
    const int hcol = h0 + hh * 64 + hq * 8;
    rowA[hh] = (long long)(b * 512 + ct * 64 + 2 * c2) * 4096 + hcol;
    float4 a0 = *(const float4*)(x + rowA[hh]);
    float4 a1 = *(const float4*)(x + rowA[hh] + 4);
    float4 b0 = *(const float4*)(x + rowA[hh] + 4096);
    float4 b1 = *(const float4*)(x + rowA[hh] + 4100);
    unsigned short ha[8], hb[8];
    ha[0]=f2bf(a0.x); ha[1]=f2bf(a0.y); ha[2]=f2bf(a0.z); ha[3]=f2bf(a0.w);
    ha[4]=f2bf(a1.x); ha[5]=f2bf(a1.y); ha[6]=f2bf(a1.z); ha[7]=f2bf(a1.w);
    hb[0]=f2bf(b0.x); hb[1]=f2bf(b0.y); hb[2]=f2bf(b0.z); hb[3]=f2bf(b0.w);
    hb[4]=f2bf(b1.x); hb[5]=f2bf(b1.y); hb[6]=f2bf(b1.z); hb[7]=f2bf(b1.w);
    pa[hh].x = (unsigned int)ha[0] | ((unsigned int)ha[1] << 16);
    pa[hh].y = (unsigned int)ha[2] | ((unsigned int)ha[3] << 16);
    pa[hh].z = (unsigned int)ha[4] | ((unsigned int)ha[5] << 16);
    pa[hh].w = (unsigned int)ha[6] | ((unsigned int)ha[7] << 16);
    pb[hh].x = (unsigned int)hb[0] | ((unsigned int)hb[1] << 16);
    pb[hh].y = (unsigned int)hb[2] | ((unsigned int)hb[3] << 16);
    pb[hh].z = (unsigned int)hb[4] | ((unsigned int)hb[5] << 16);
    pb[hh].w = (unsigned int)hb[6] | ((unsigned int)hb[7] << 16);
    uint4 u0, u1;
    u0.x = (unsigned int)ha[0] | ((unsigned int)hb[0] << 16);
    u0.y = (unsigned int)ha[1] | ((unsigned int)hb[1] << 16);
    u0.z = (unsigned int)ha[2] | ((unsigned int)hb[2] << 16);
    u0.w = (unsigned int)ha[3] | ((unsigned int)hb[3] << 16);
    u1.x = (unsigned int)ha[4] | ((unsigned int)hb[4] << 16);
    u1.y = (unsigned int)ha[5] | ((unsigned int)hb[5] << 16);
    u1.z = (unsigned int)ha[6] | ((unsigned int)hb[6] << 16);
    u1.w = (unsigned int)ha[7] | ((unsigned int)hb[7] << 16);
    *(uint4*)&T[hh][c2][hq * 8]     = u0;   // h slots hq*8 .. +3
    *(uint4*)&T[hh][c2][hq * 8 + 4] = u1;   // h slots hq*8+4 .. +7
  }
  asm volatile("s_waitcnt lgkmcnt(0)" ::: "memory");  // LDS writes only
  __builtin_amdgcn_s_barrier();
  // straight x_bf stores post-barrier (consumed by gsym soon -> keep cached)
  #pragma unroll
  for (int hh = 0; hh < 2; ++hh) {
    *(uint4*)(x_bf + rowA[hh])        = pa[hh];
    *(uint4*)(x_bf + rowA[hh] + 4096) = pb[hh];
  }
  // phase 2: thread owns (hh2, h4, c8): 4 h-rows x 8 c-cols of xT
  const int hh2 = tid >> 7;               // tile half
  const int h4  = (tid >> 3) & 15;        // 16 h-quads
  const int c8  = tid & 7;                // 8 c-groups of 8
  unsigned int rv[4][4];
  #pragma unroll
  for (int i = 0; i < 4; ++i) {
    uint4 t = *(const uint4*)&T[hh2][c8 * 4 + i][h4 * 4];
    rv[i][0] = t.x; rv[i][1] = t.y; rv[i][2] = t.z; rv[i][3] = t.w;
  }
  #pragma unroll
  for (int r = 0; r < 4; ++r) {
    u32x4 o = { rv[0][r], rv[1][r], rv[2][r], rv[3][r] };
    __builtin_nontemporal_store(o,
        (u32x4*)(xT + ((long long)(b * 4096 + h0 + hh2 * 64 + h4 * 4 + r) * 512
                       + ct * 64 + c8 * 8)));
  }
}

// ---------------------------------------------------------------------------
// G = X X^T, symmetric + split-K, 2-deep counted-vmcnt pipeline. 128^2 tiles.
// LDS 32 KB -> 5 blocks/CU. NLOAD=4/stage; steady wait vmcnt(4), tail 0.
// Partials written BF16.
// ---------------------------------------------------------------------------
__global__ __launch_bounds__(256)
void gemm_gsym(const unsigned short* __restrict__ X, unsigned short* __restrict__ P) {
  constexpr int HALF = 128 * 32;           // shorts per buffer (8 KB)
  __shared__ unsigned short As[2 * HALF];
  __shared__ unsigned short Bs[2 * HALF];
  const int tid = threadIdx.x;
  const int l   = tid & 63;
  const int w   = tid >> 6;
  const int wr  = w >> 1, wc = w & 1;
  const int b   = blockIdx.y;
  const int t   = blockIdx.x >> 2;
  const int split = blockIdx.x & 3;
  int tm, tn; sym_tile_decode(t, tm, tn);

  const unsigned short* Ab = X + (long long)b * 2097152 + (long long)(tm * 128) * 4096;
  const unsigned short* Bb = X + (long long)b * 2097152 + (long long)(tn * 128) * 4096;

  f32x4 acc[4][4];
  #pragma unroll
  for (int m = 0; m < 4; ++m)
    #pragma unroll
    for (int n = 0; n < 4; ++n) acc[m][n] = (f32x4){0.f, 0.f, 0.f, 0.f};

  const int srow = tid >> 2;
  const int scol = ((tid & 3) ^ ((tid >> 3) & 3)) * 8;
  const int ch8  = (((l >> 4) ^ ((l >> 1) & 3)) * 8);

  auto stage = [&](int buf, int k0) {
    #pragma unroll
    for (int i = 0; i < 2; ++i)
      gld_lds16(Ab + (long long)(i * 64 + srow) * 4096 + k0 + scol, &As[buf * HALF + i * 2048 + tid * 8]);
    #pragma unroll
    for (int i = 0; i < 2; ++i)
      gld_lds16(Bb + (long long)(i * 64 + srow) * 4096 + k0 + scol, &Bs[buf * HALF + i * 2048 + tid * 8]);
  };
  auto compute = [&](int buf) {
    bf16x8 af[4], bfr[4];
    #pragma unroll
    for (int m = 0; m < 4; ++m)
      af[m] = *(const bf16x8*)&As[buf * HALF + (wr * 64 + m * 16 + (l & 15)) * 32 + ch8];
    #pragma unroll
    for (int n = 0; n < 4; ++n)
      bfr[n] = *(const bf16x8*)&Bs[buf * HALF + (wc * 64 + n * 16 + (l & 15)) * 32 + ch8];
    __builtin_amdgcn_s_setprio(1);
    #pragma unroll
    for (int m = 0; m < 4; ++m)
      #pragma unroll
      for (int n = 0; n < 4; ++n)
        acc[m][n] = __builtin_amdgcn_mfma_f32_16x16x32_bf16(af[m], bfr[n], acc[m][n], 0, 0, 0);
    __builtin_amdgcn_s_setprio(0);
  };

  const int k_beg = split * 1024;
  constexpr int NK = 32;
  stage(0, k_beg);
  stage(1, k_beg + 32);
  int ks = k_beg + 64;
  for (int k = 0; k < NK - 2; ++k) {
    vm_wait<4>();                           // oldest stage (buf k&1) retired
    CFENCE(); __builtin_amdgcn_s_barrier(); CFENCE();
    compute(k & 1);
    CFENCE(); __builtin_amdgcn_s_barrier(); CFENCE();
    stage(k & 1, ks); ks += 32;             // refill freed buffer
  }
  vm_wait<4>();
  CFENCE(); __builtin_amdgcn_s_barrier(); CFENCE();
  compute((NK - 2) & 1);
  vm_wait<0>();
  CFENCE(); __builtin_amdgcn_s_barrier(); CFENCE();
  compute((NK - 1) & 1);

  unsigned short* Pt = P + (((long long)b * 10 + t) * 4 + split) * 16384;
  const int cc = l & 15, r4 = (l >> 4) * 4;
  #pragma unroll
  for (int m = 0; m < 4; ++m) {
    #pragma unroll
    for (int n = 0; n < 4; ++n) {
      const int row = wr * 64 + m * 16 + r4;
      const int col = wc * 64 + n * 16 + cc;
      #pragma unroll
      for (int j = 0; j < 4; ++j)
        Pt[(row + j) * 128 + col] = f2bf(acc[m][n][j]);
    }
  }
}

// ---------------------------------------------------------------------------
// Reduce 4 bf16 split-K partials (fp32 sum) -> bf16 G tile; mirror off-diag.
// ---------------------------------------------------------------------------
__global__ __launch_bounds__(256)
void reduce_mirror(const unsigned short* __restrict__ P, unsigned short* __restrict__ G) {
  __shared__ unsigned short T[128 * 129];
  const int tid = threadIdx.x;
  const int b = blockIdx.y;
  const int t = blockIdx.x;
  int tm, tn; sym_tile_decode(t, tm, tn);
  const unsigned short* Pt = P + ((long long)(b * 10 + t) * 4) * 16384;
  unsigned short* Gb = G + (long long)b * 262144;

  #pragma unroll
  for (int e = 0; e < 16; ++e) {
    const int v = e * 256 + tid;            // ushort4 index (4 elems/thread)
    ushort4 s0 = ((const ushort4*)Pt)[v];
    ushort4 s1 = ((const ushort4*)(Pt + 16384))[v];
    ushort4 s2 = ((const ushort4*)(Pt + 32768))[v];
    ushort4 s3 = ((const ushort4*)(Pt + 49152))[v];
    unsigned int h0 = f2bf(bf2f(s0.x) + bf2f(s1.x) + bf2f(s2.x) + bf2f(s3.x));
    unsigned int h1 = f2bf(bf2f(s0.y) + bf2f(s1.y) + bf2f(s2.y) + bf2f(s3.y));
    unsigned int h2 = f2bf(bf2f(s0.z) + bf2f(s1.z) + bf2f(s2.z) + bf2f(s3.z));
    unsigned int h3 = f2bf(bf2f(s0.w) + bf2f(s1.w) + bf2f(s2.w) + bf2f(s3.w));
    const int idx = v * 4;
    const int r = idx >> 7, c = idx & 127;
    unsigned int* gp = (unsigned int*)(Gb + (long long)(tm * 128 + r) * 512 + tn * 128 + c);
    gp[0] = h0 | (h1 << 16);
    gp[1] = h2 | (h3 << 16);
    unsigned short* tp = &T[r * 129 + c];
    tp[0] = (unsigned short)h0; tp[1] = (unsigned short)h1;
    tp[2] = (unsigned short)h2; tp[3] = (unsigned short)h3;
  }
  if (tm != tn) {
    __syncthreads();
    #pragma unroll
    for (int e = 0; e < 16; ++e) {
      const int idx = (e * 256 + tid) * 4;
      const int r = idx >> 7, c = idx & 127;
      unsigned int o0 = T[(c + 0) * 129 + r], o1 = T[(c + 1) * 129 + r];
      unsigned int o2 = T[(c + 2) * 129 + r], o3 = T[(c + 3) * 129 + r];
      unsigned int* gp = (unsigned int*)(Gb + (long long)(tn * 128 + r) * 512 + tm * 128 + c);
      gp[0] = o0 | (o1 << 16);
      gp[1] = o2 | (o3 << 16);
    }
  }
}

// ---------------------------------------------------------------------------
// Batched GEMM C = A * B^T, 2-deep counted-vmcnt pipeline, swizzled LDS.
// FR=2 -> 64^2 tile (NLOAD=2), FR=4 -> 128^2 tile (NLOAD=4). LDS 8/32 KB.
// NT: non-temporal C stores (for final out, never re-read).
// ---------------------------------------------------------------------------
template<int FR, int NT>
__global__ __launch_bounds__(256)
void gemm_bt4(const unsigned short* __restrict__ A, const unsigned short* __restrict__ B,
              float* __restrict__ C,
              int N, int K, int sA, int sB,
              long long bsA, long long bsB, long long bsC, int Ntiles) {
  constexpr int BMN = FR * 32;
  constexpr int ISS = BMN / 64;
  constexpr int HALF = BMN * 32;            // shorts per buffer
  constexpr int NLOAD = 2 * ISS;            // gld_lds per stage
  __shared__ unsigned short As[2 * HALF];
  __shared__ unsigned short Bs[2 * HALF];

  const int tid = threadIdx.x;
  const int l   = tid & 63;
  const int w   = tid >> 6;
  const int wr  = w >> 1, wc = w & 1;
  const int bz  = blockIdx.y;
  const int tm  = blockIdx.x / Ntiles;
  const int tn  = blockIdx.x % Ntiles;

  const unsigned short* Ab = A + bz * bsA + (long long)(tm * BMN) * sA;
  const unsigned short* Bb = B + bz * bsB + (long long)(tn * BMN) * sB;

  f32x4 acc[FR][FR];
  #pragma unroll
  for (int m = 0; m < FR; ++m)
    #pragma unroll
    for (int n = 0; n < FR; ++n) acc[m][n] = (f32x4){0.f, 0.f, 0.f, 0.f};

  const int srow = tid >> 2;
  const int scol = ((tid & 3) ^ ((tid >> 3) & 3)) * 8;  // pre-swizzled source chunk
  const int ch8  = (((l >> 4) ^ ((l >> 1) & 3)) * 8);   // swizzled read chunk

  auto stage = [&](int buf, int k0) {
    #pragma unroll
    for (int i = 0; i < ISS; ++i)
      gld_lds16(Ab + (long long)(i * 64 + srow) * sA + k0 + scol, &As[buf * HALF + i * 2048 + tid * 8]);
    #pragma unroll
    for (int i = 0; i < ISS; ++i)
      gld_lds16(Bb + (long long)(i * 64 + srow) * sB + k0 + scol, &Bs[buf * HALF + i * 2048 + tid * 8]);
  };
  auto compute = [&](int buf) {
    bf16x8 af[FR], bfr[FR];
    #pragma unroll
    for (int m = 0; m < FR; ++m)
      af[m] = *(const bf16x8*)&As[buf * HALF + (wr * (FR * 16) + m * 16 + (l & 15)) * 32 + ch8];
    #pragma unroll
    for (int n = 0; n < FR; ++n)
      bfr[n] = *(const bf16x8*)&Bs[buf * HALF + (wc * (FR * 16) + n * 16 + (l & 15)) * 32 + ch8];
    __builtin_amdgcn_s_setprio(1);
    #pragma unroll
    for (int m = 0; m < FR; ++m)
      #pragma unroll
      for (int n = 0; n < FR; ++n)
        acc[m][n] = __builtin_amdgcn_mfma_f32_16x16x32_bf16(af[m], bfr[n], acc[m][n], 0, 0, 0);
    __builtin_amdgcn_s_setprio(0);
  };

  const int nk = K >> 5;
  stage(0, 0);
  stage(1, 32);
  int ks = 64;
  for (int k = 0; k < nk - 2; ++k) {
    vm_wait<NLOAD>();                       // oldest stage (buf k&1) retired
    CFENCE(); __builtin_amdgcn_s_barrier(); CFENCE();
    compute(k & 1);
    CFENCE(); __builtin_amdgcn_s_barrier(); CFENCE();
    stage(k & 1, ks); ks += 32;             // refill freed buffer
  }
  vm_wait<NLOAD>();
  CFENCE(); __builtin_amdgcn_s_barrier(); CFENCE();
  compute(nk & 1);                          // (nk-2)&1 == nk&1
  vm_wait<0>();
  CFENCE(); __builtin_amdgcn_s_barrier(); CFENCE();
  compute((nk - 1) & 1);

  const int cc = l & 15, r4 = (l >> 4) * 4;
  const int row0 = tm * BMN + wr * (FR * 16);
  const int col0 = tn * BMN + wc * (FR * 16);
  #pragma unroll
  for (int m = 0; m < FR; ++m) {
    #pragma unroll
    for (int n = 0; n < FR; ++n) {
      const int row = row0 + m * 16 + r4;
      const int col = col0 + n * 16 + cc;
      long long base = bz * bsC + (long long)row * N + col;
      #pragma unroll
      for (int j = 0; j < 4; ++j) {
        if constexpr (NT) __builtin_nontemporal_store(acc[m][n][j], &C[base + (long long)j * N]);
        else              C[base + (long long)j * N] = acc[m][n][j];
      }
    }
  }
}

// ---------------------------------------------------------------------------
// Row softmax: s [8192 rows][512] f32 -> p_bf [8192][512] bf16
// ---------------------------------------------------------------------------
__global__ __launch_bounds__(256)
void row_softmax_kernel(const float* __restrict__ s, unsigned short* __restrict__ p_bf) {
  __shared__ float red[4], red2[4];
  const float* p = s + (long long)blockIdx.x * 512;
  unsigned short* q = p_bf + (long long)blockIdx.x * 512;
  const int tid = threadIdx.x;
  float v0 = p[tid], v1 = p[tid + 256];
  float m = fmaxf(v0, v1);
  #pragma unroll
  for (int i = 1; i < 64; i <<= 1) m = fmaxf(m, __shfl_xor(m, i));
  if ((tid & 63) == 0) red[tid >> 6] = m;
  __syncthreads();
  m = fmaxf(fmaxf(red[0], red[1]), fmaxf(red[2], red[3]));
  float e0 = __expf(v0 - m), e1 = __expf(v1 - m);
  float sum = e0 + e1;
  #pragma unroll
  for (int i = 1; i < 64; i <<= 1) sum += __shfl_xor(sum, i);
  if ((tid & 63) == 0) red2[tid >> 6] = sum;
  __syncthreads();
  sum = (red2[0] + red2[1]) + (red2[2] + red2[3]);
  float inv = 1.0f / sum;
  q[tid] = f2bf(e0 * inv);
  q[tid + 256] = f2bf(e1 * inv);
}

// ---------------------------------------------------------------------------
// Column softmax (axis 1) + identity fold. grid (16,16), 256 threads:
// 32 d-columns x 8 c-strips of 64 rows, LDS partial reduce.
// ---------------------------------------------------------------------------
__global__ __launch_bounds__(256)
void col_softmax_kernel(const unsigned short* __restrict__ p_bf, unsigned short* __restrict__ a_bf) {
  __shared__ float cs[8][32];
  const int tid = threadIdx.x;
  const int dl = tid & 31;
  const int st = tid >> 5;
  const int d  = blockIdx.x * 32 + dl;
  const long long base = (long long)blockIdx.y * 262144 + d;
  const unsigned short* p = p_bf + base;
  float sum = 0.f;
  #pragma unroll 4
  for (int c = st * 64; c < st * 64 + 64; ++c)
    sum += __expf(bf2f(p[(long long)c * 512]));
  cs[st][dl] = sum;
  __syncthreads();
  if (st == 0) {
    float s = ((cs[0][dl] + cs[1][dl]) + (cs[2][dl] + cs[3][dl]))
            + ((cs[4][dl] + cs[5][dl]) + (cs[6][dl] + cs[7][dl]));
    cs[0][dl] = 1.0f / s;
  }
  __syncthreads();
  const float inv = cs[0][dl];
  unsigned short* q = a_bf + base;
  #pragma unroll 4
  for (int c = st * 64; c < st * 64 + 64; ++c) {
    float v = __expf(bf2f(p[(long long)c * 512])) * inv;
    if (c == d) v += 1.0f;               // residual fold: out = (a+I) @ X
    q[(long long)c * 512] = f2bf(v);
  }
}

// ---------------------------------------------------------------------------
extern "C" void kernel_launch(void* const* d_in, const int* in_sizes, int n_in,
                              void* d_out, int out_size, void* d_ws, size_t ws_size,
                              hipStream_t stream) {
  (void)in_sizes; (void)n_in; (void)out_size; (void)ws_size;
  const float* x = (const float*)d_in[0];   // [16][512][4096]
  const float* W = (const float*)d_in[1];   // [512][512]
  float* out = (float*)d_out;               // [16][512][4096] = 128 MiB
  char* ws = (char*)d_ws;

  // d_out scratch (dead before final gemm overwrites it):
  unsigned short* x_bf = (unsigned short*)d_out;              // [0, 64 MiB)
  unsigned short* P = (unsigned short*)((char*)d_out + 67108864); // [64,84 MiB) bf16 splitK partials
  unsigned short* p_bf = (unsigned short*)((char*)d_out + 88080384); // [84,92 MiB), disjoint from P

  // ws layout (88.5 MiB high water, known-safe):
  unsigned short* xT   = (unsigned short*)ws;                 // [0, 64 MiB)
  unsigned short* G_bf = (unsigned short*)(ws + 67108864);    // 8 MiB
  float*          s_f  = (float*)(ws + 75497472);             // 16 MiB
  unsigned short* W_bf = (unsigned short*)(ws + 92274688);    // 0.5 MiB
  unsigned short* a_bf = G_bf;   // aliases G_bf (dead after s-gemm)

  // 1) x read once: -> x_bf (d_out) + xT (ws); W -> bf16
  fused_cvt_transpose<<<dim3(256, 16), 256, 0, stream>>>(x, x_bf, xT);
  cvt_kernel<<<256, 256, 0, stream>>>(W, W_bf, 65536);

  // 2) G = X X^T: symmetric tiles (10 of 16) x 4 K-splits -> bf16 partials
  gemm_gsym<<<dim3(40, 16), 256, 0, stream>>>(x_bf, P);

  // 3) reduce partials (fp32 sum), write bf16 G (+ mirrored transpose)
  reduce_mirror<<<dim3(10, 16), 256, 0, stream>>>(P, G_bf);

  // 4) s = G W^T (f32). M=N=K=512; W batch-shared (bsB=0).
  gemm_bt4<2, 0><<<dim3(64, 16), 256, 0, stream>>>(
      G_bf, W_bf, s_f,
      512, 512, 512, 512, 262144LL, 0LL, 262144LL, 8);

  // 5) softmax over d (rows, -> bf16 p), then over c (cols) + I -> a (bf16)
  row_softmax_kernel<<<8192, 256, 0, stream>>>(s_f, p_bf);
  col_softmax_kernel<<<dim3(16, 16), 256, 0, stream>>>(p_bf, a_bf);

  // 6) out = (a+I) @ X. 128^2 tiles; NT stores (out never re-read).
  gemm_bt4<4, 1><<<dim3(128, 16), 256, 0, stream>>>(
      a_bf, xT, out,
      4096, 512, 512, 512, 262144LL, 2097152LL, 2097152LL, 32);
}

// Round 13
// 164.942 us; speedup vs baseline: 1.1182x; 1.1182x over previous
//
#include <hip/hip_runtime.h>

// ---------------------------------------------------------------------------
// WAM_13056700579937: out = softmax_ax1(softmax_ax2((X X^T) W^T)) @ X + X
// B=16, C=512, HW=4096. fp32 in/out; internal bf16 MFMA (16x16x32).
//
// Round 13: xT eliminated. Transpose folded into out-gemm B-staging
// (reg-pack -> LDS [16dpair][132] u32, b32 frag reads). Transpose kernel
// becomes a pure streaming cvt. One barrier per K-step in out-gemm.
// ---------------------------------------------------------------------------

typedef __attribute__((ext_vector_type(8))) short bf16x8;   // 8 bf16 = 4 VGPR
typedef __attribute__((ext_vector_type(4))) float f32x4;

#define DEVINL __device__ __forceinline__
#define CFENCE() asm volatile("" ::: "memory")

DEVINL unsigned short f2bf(float f) {   // RNE float->bf16 (finite inputs)
  union { float f; unsigned int u; } c; c.f = f;
  unsigned int u = c.u;
  u += 0x7fffu + ((u >> 16) & 1u);
  return (unsigned short)(u >> 16);
}

DEVINL float bf2f(unsigned short h) {
  union { unsigned int u; float f; } c; c.u = ((unsigned int)h) << 16;
  return c.f;
}

DEVINL void gld_lds16(const unsigned short* g, unsigned short* l) {
  __builtin_amdgcn_global_load_lds(
      (const __attribute__((address_space(1))) unsigned int*)g,
      (__attribute__((address_space(3))) unsigned int*)l,
      16 /*bytes, literal*/, 0, 0);
}

template<int N> DEVINL void vm_wait() {
  if constexpr (N == 0)       asm volatile("s_waitcnt vmcnt(0)" ::: "memory");
  else if constexpr (N == 2)  asm volatile("s_waitcnt vmcnt(2)" ::: "memory");
  else if constexpr (N == 4)  asm volatile("s_waitcnt vmcnt(4)" ::: "memory");
  else if constexpr (N == 6)  asm volatile("s_waitcnt vmcnt(6)" ::: "memory");
  else if constexpr (N == 8)  asm volatile("s_waitcnt vmcnt(8)" ::: "memory");
  else static_assert(N < 0, "unsupported vmcnt");
}

DEVINL void lgkm0() { asm volatile("s_waitcnt lgkmcnt(0)" ::: "memory"); }

DEVINL void sym_tile_decode(int t, int& tm, int& tn) {  // t in [0,10) -> upper 4x4
  if (t < 4)      { tm = 0; tn = t; }
  else if (t < 7) { tm = 1; tn = t - 3; }
  else if (t < 9) { tm = 2; tn = t - 5; }
  else            { tm = 3; tn = 3; }
}

// ---------------------------------------------------------------------------
// cvt fp32 -> bf16 (x and W). Pure streaming.
// ---------------------------------------------------------------------------
__global__ __launch_bounds__(256)
void cvt_kernel(const float* __restrict__ in, unsigned short* __restrict__ out, int n4) {
  int i = blockIdx.x * 256 + threadIdx.x;
  const int stride = gridDim.x * 256;
  for (; i < n4; i += stride) {
    float4 v = ((const float4*)in)[i];
    unsigned int lo = (unsigned int)f2bf(v.x) | ((unsigned int)f2bf(v.y) << 16);
    unsigned int hi = (unsigned int)f2bf(v.z) | ((unsigned int)f2bf(v.w) << 16);
    uint2 o; o.x = lo; o.y = hi;
    ((uint2*)out)[i] = o;
  }
}

// ---------------------------------------------------------------------------
// G = X X^T, symmetric + split-K, 2-deep counted-vmcnt pipeline. 128^2 tiles.
// Partials written BF16.
// ---------------------------------------------------------------------------
__global__ __launch_bounds__(256)
void gemm_gsym(const unsigned short* __restrict__ X, unsigned short* __restrict__ P) {
  constexpr int HALF = 128 * 32;           // shorts per buffer (8 KB)
  __shared__ unsigned short As[2 * HALF];
  __shared__ unsigned short Bs[2 * HALF];
  const int tid = threadIdx.x;
  const int l   = tid & 63;
  const int w   = tid >> 6;
  const int wr  = w >> 1, wc = w & 1;
  const int b   = blockIdx.y;
  const int t   = blockIdx.x >> 2;
  const int split = blockIdx.x & 3;
  int tm, tn; sym_tile_decode(t, tm, tn);

  const unsigned short* Ab = X + (long long)b * 2097152 + (long long)(tm * 128) * 4096;
  const unsigned short* Bb = X + (long long)b * 2097152 + (long long)(tn * 128) * 4096;

  f32x4 acc[4][4];
  #pragma unroll
  for (int m = 0; m < 4; ++m)
    #pragma unroll
    for (int n = 0; n < 4; ++n) acc[m][n] = (f32x4){0.f, 0.f, 0.f, 0.f};

  const int srow = tid >> 2;
  const int scol = ((tid & 3) ^ ((tid >> 3) & 3)) * 8;
  const int ch8  = (((l >> 4) ^ ((l >> 1) & 3)) * 8);

  auto stage = [&](int buf, int k0) {
    #pragma unroll
    for (int i = 0; i < 2; ++i)
      gld_lds16(Ab + (long long)(i * 64 + srow) * 4096 + k0 + scol, &As[buf * HALF + i * 2048 + tid * 8]);
    #pragma unroll
    for (int i = 0; i < 2; ++i)
      gld_lds16(Bb + (long long)(i * 64 + srow) * 4096 + k0 + scol, &Bs[buf * HALF + i * 2048 + tid * 8]);
  };
  auto compute = [&](int buf) {
    bf16x8 af[4], bfr[4];
    #pragma unroll
    for (int m = 0; m < 4; ++m)
      af[m] = *(const bf16x8*)&As[buf * HALF + (wr * 64 + m * 16 + (l & 15)) * 32 + ch8];
    #pragma unroll
    for (int n = 0; n < 4; ++n)
      bfr[n] = *(const bf16x8*)&Bs[buf * HALF + (wc * 64 + n * 16 + (l & 15)) * 32 + ch8];
    __builtin_amdgcn_s_setprio(1);
    #pragma unroll
    for (int m = 0; m < 4; ++m)
      #pragma unroll
      for (int n = 0; n < 4; ++n)
        acc[m][n] = __builtin_amdgcn_mfma_f32_16x16x32_bf16(af[m], bfr[n], acc[m][n], 0, 0, 0);
    __builtin_amdgcn_s_setprio(0);
  };

  const int k_beg = split * 1024;
  constexpr int NK = 32;
  stage(0, k_beg);
  stage(1, k_beg + 32);
  int ks = k_beg + 64;
  for (int k = 0; k < NK - 2; ++k) {
    vm_wait<4>();                           // oldest stage (buf k&1) retired
    CFENCE(); __builtin_amdgcn_s_barrier(); CFENCE();
    compute(k & 1);
    CFENCE(); __builtin_amdgcn_s_barrier(); CFENCE();
    stage(k & 1, ks); ks += 32;             // refill freed buffer
  }
  vm_wait<4>();
  CFENCE(); __builtin_amdgcn_s_barrier(); CFENCE();
  compute((NK - 2) & 1);
  vm_wait<0>();
  CFENCE(); __builtin_amdgcn_s_barrier(); CFENCE();
  compute((NK - 1) & 1);

  unsigned short* Pt = P + (((long long)b * 10 + t) * 4 + split) * 16384;
  const int cc = l & 15, r4 = (l >> 4) * 4;
  #pragma unroll
  for (int m = 0; m < 4; ++m) {
    #pragma unroll
    for (int n = 0; n < 4; ++n) {
      const int row = wr * 64 + m * 16 + r4;
      const int col = wc * 64 + n * 16 + cc;
      #pragma unroll
      for (int j = 0; j < 4; ++j)
        Pt[(row + j) * 128 + col] = f2bf(acc[m][n][j]);
    }
  }
}

// ---------------------------------------------------------------------------
// Reduce 4 bf16 split-K partials (fp32 sum) -> bf16 G tile; mirror off-diag.
// ---------------------------------------------------------------------------
__global__ __launch_bounds__(256)
void reduce_mirror(const unsigned short* __restrict__ P, unsigned short* __restrict__ G) {
  __shared__ unsigned short T[128 * 129];
  const int tid = threadIdx.x;
  const int b = blockIdx.y;
  const int t = blockIdx.x;
  int tm, tn; sym_tile_decode(t, tm, tn);
  const unsigned short* Pt = P + ((long long)(b * 10 + t) * 4) * 16384;
  unsigned short* Gb = G + (long long)b * 262144;

  #pragma unroll
  for (int e = 0; e < 16; ++e) {
    const int v = e * 256 + tid;            // ushort4 index (4 elems/thread)
    ushort4 s0 = ((const ushort4*)Pt)[v];
    ushort4 s1 = ((const ushort4*)(Pt + 16384))[v];
    ushort4 s2 = ((const ushort4*)(Pt + 32768))[v];
    ushort4 s3 = ((const ushort4*)(Pt + 49152))[v];
    unsigned int h0 = f2bf(bf2f(s0.x) + bf2f(s1.x) + bf2f(s2.x) + bf2f(s3.x));
    unsigned int h1 = f2bf(bf2f(s0.y) + bf2f(s1.y) + bf2f(s2.y) + bf2f(s3.y));
    unsigned int h2 = f2bf(bf2f(s0.z) + bf2f(s1.z) + bf2f(s2.z) + bf2f(s3.z));
    unsigned int h3 = f2bf(bf2f(s0.w) + bf2f(s1.w) + bf2f(s2.w) + bf2f(s3.w));
    const int idx = v * 4;
    const int r = idx >> 7, c = idx & 127;
    unsigned int* gp = (unsigned int*)(Gb + (long long)(tm * 128 + r) * 512 + tn * 128 + c);
    gp[0] = h0 | (h1 << 16);
    gp[1] = h2 | (h3 << 16);
    unsigned short* tp = &T[r * 129 + c];
    tp[0] = (unsigned short)h0; tp[1] = (unsigned short)h1;
    tp[2] = (unsigned short)h2; tp[3] = (unsigned short)h3;
  }
  if (tm != tn) {
    __syncthreads();
    #pragma unroll
    for (int e = 0; e < 16; ++e) {
      const int idx = (e * 256 + tid) * 4;
      const int r = idx >> 7, c = idx & 127;
      unsigned int o0 = T[(c + 0) * 129 + r], o1 = T[(c + 1) * 129 + r];
      unsigned int o2 = T[(c + 2) * 129 + r], o3 = T[(c + 3) * 129 + r];
      unsigned int* gp = (unsigned int*)(Gb + (long long)(tn * 128 + r) * 512 + tm * 128 + c);
      gp[0] = o0 | (o1 << 16);
      gp[1] = o2 | (o3 << 16);
    }
  }
}

// ---------------------------------------------------------------------------
// s-gemm: C = A * B^T, 64^2 tiles, 2-deep counted-vmcnt pipeline (NLOAD=2).
// ---------------------------------------------------------------------------
__global__ __launch_bounds__(256)
void gemm_s(const unsigned short* __restrict__ A, const unsigned short* __restrict__ B,
            float* __restrict__ C) {
  constexpr int HALF = 64 * 32;
  __shared__ unsigned short As[2 * HALF];
  __shared__ unsigned short Bs[2 * HALF];

  const int tid = threadIdx.x;
  const int l   = tid & 63;
  const int w   = tid >> 6;
  const int wr  = w >> 1, wc = w & 1;
  const int bz  = blockIdx.y;
  const int tm  = blockIdx.x >> 3;
  const int tn  = blockIdx.x & 7;

  const unsigned short* Ab = A + (long long)bz * 262144 + (long long)(tm * 64) * 512;
  const unsigned short* Bb = B + (long long)(tn * 64) * 512;

  f32x4 acc[2][2];
  #pragma unroll
  for (int m = 0; m < 2; ++m)
    #pragma unroll
    for (int n = 0; n < 2; ++n) acc[m][n] = (f32x4){0.f, 0.f, 0.f, 0.f};

  const int srow = tid >> 2;
  const int scol = ((tid & 3) ^ ((tid >> 3) & 3)) * 8;
  const int ch8  = (((l >> 4) ^ ((l >> 1) & 3)) * 8);

  auto stage = [&](int buf, int k0) {
    gld_lds16(Ab + (long long)srow * 512 + k0 + scol, &As[buf * HALF + tid * 8]);
    gld_lds16(Bb + (long long)srow * 512 + k0 + scol, &Bs[buf * HALF + tid * 8]);
  };
  auto compute = [&](int buf) {
    bf16x8 af[2], bfr[2];
    #pragma unroll
    for (int m = 0; m < 2; ++m)
      af[m] = *(const bf16x8*)&As[buf * HALF + (wr * 32 + m * 16 + (l & 15)) * 32 + ch8];
    #pragma unroll
    for (int n = 0; n < 2; ++n)
      bfr[n] = *(const bf16x8*)&Bs[buf * HALF + (wc * 32 + n * 16 + (l & 15)) * 32 + ch8];
    __builtin_amdgcn_s_setprio(1);
    #pragma unroll
    for (int m = 0; m < 2; ++m)
      #pragma unroll
      for (int n = 0; n < 2; ++n)
        acc[m][n] = __builtin_amdgcn_mfma_f32_16x16x32_bf16(af[m], bfr[n], acc[m][n], 0, 0, 0);
    __builtin_amdgcn_s_setprio(0);
  };

  stage(0, 0);
  stage(1, 32);
  int ks = 64;
  for (int k = 0; k < 14; ++k) {
    vm_wait<2>();
    CFENCE(); __builtin_amdgcn_s_barrier(); CFENCE();
    compute(k & 1);
    CFENCE(); __builtin_amdgcn_s_barrier(); CFENCE();
    stage(k & 1, ks); ks += 32;
  }
  vm_wait<2>();
  CFENCE(); __builtin_amdgcn_s_barrier(); CFENCE();
  compute(0);
  vm_wait<0>();
  CFENCE(); __builtin_amdgcn_s_barrier(); CFENCE();
  compute(1);

  const int cc = l & 15, r4 = (l >> 4) * 4;
  const int row0 = tm * 64 + wr * 32;
  const int col0 = tn * 64 + wc * 32;
  #pragma unroll
  for (int m = 0; m < 2; ++m) {
    #pragma unroll
    for (int n = 0; n < 2; ++n) {
      const int row = row0 + m * 16 + r4;
      const int col = col0 + n * 16 + cc;
      long long base = (long long)bz * 262144 + (long long)row * 512 + col;
      #pragma unroll
      for (int j = 0; j < 4; ++j)
        C[base + (long long)j * 512] = acc[m][n][j];
    }
  }
}

// ---------------------------------------------------------------------------
// out-gemm with FUSED B-transpose: C[c][h] = sum_d A[c][d] * X[d][h].
// A = a_bf (K=d contiguous) via gld_lds (XOR-swizzle, identity k-mapping).
// B = x_bf rows [d][h]: reg-load 2 d-rows x 8 h, vertical u32 pack,
// ds_write_b128 into Bs[buf][dpair 16][132 u32] (h + 4 pad). Frag read:
// lane l, n: 4x ds_read_b32 at rows p0..p0+3, col h -> bf16x8 (k ascending,
// identity mapping, matches A). 2-deep, ONE barrier/K-step, counted vmcnt:
// per iter issues 2 B-loads + 2 A-gld; waits: <4> before compute (A(k) in),
// <2> before ds_write (B(k+1) regs in, covered by compute latency).
// ---------------------------------------------------------------------------
__global__ __launch_bounds__(256)
void gemm_out(const unsigned short* __restrict__ A, const unsigned short* __restrict__ X,
              float* __restrict__ C) {
  __shared__ unsigned short As[2][128 * 32];   // 16 KB
  __shared__ unsigned int   Bs[2][16][132];    // 16.5 KB

  const int tid = threadIdx.x;
  const int l   = tid & 63;
  const int w   = tid >> 6;
  const int wr  = w >> 1, wc = w & 1;
  const int bz  = blockIdx.y;
  const int tm  = blockIdx.x >> 5;    // 4 M-tiles (128 c)
  const int tn  = blockIdx.x & 31;    // 32 N-tiles (128 h)

  const unsigned short* Ab = A + (long long)bz * 262144  + (long long)(tm * 128) * 512;
  const unsigned short* Xb = X + (long long)bz * 2097152 + tn * 128;

  f32x4 acc[4][4];
  #pragma unroll
  for (int m = 0; m < 4; ++m)
    #pragma unroll
    for (int n = 0; n < 4; ++n) acc[m][n] = (f32x4){0.f, 0.f, 0.f, 0.f};

  const int srow = tid >> 2;
  const int scol = ((tid & 3) ^ ((tid >> 3) & 3)) * 8;
  const int ch8  = (((l >> 4) ^ ((l >> 1) & 3)) * 8);
  const int bp_  = tid >> 4;          // dpair 0..15
  const int bh_  = tid & 15;          // h-octet 0..15
  const unsigned short* Bsrc = Xb + (long long)(2 * bp_) * 4096 + bh_ * 8;

  auto Agload = [&](int buf, int k0) {
    #pragma unroll
    for (int i = 0; i < 2; ++i)
      gld_lds16(Ab + (long long)(i * 64 + srow) * 512 + k0 + scol, &As[buf][i * 2048 + tid * 8]);
  };
  auto Bload = [&](int k0, uint4& g0, uint4& g1) {
    g0 = *(const uint4*)(Bsrc + (long long)k0 * 4096);        // row d = k0 + 2p
    g1 = *(const uint4*)(Bsrc + (long long)(k0 + 1) * 4096);  // row d = k0 + 2p + 1
  };
  auto Bdswrite = [&](int buf, const uint4& g0, const uint4& g1) {
    unsigned int w0 = (g0.x & 0xffffu) | (g1.x << 16);
    unsigned int w1 = (g0.x >> 16)    | (g1.x & 0xffff0000u);
    unsigned int w2 = (g0.y & 0xffffu) | (g1.y << 16);
    unsigned int w3 = (g0.y >> 16)    | (g1.y & 0xffff0000u);
    unsigned int w4 = (g0.z & 0xffffu) | (g1.z << 16);
    unsigned int w5 = (g0.z >> 16)    | (g1.z & 0xffff0000u);
    unsigned int w6 = (g0.w & 0xffffu) | (g1.w << 16);
    unsigned int w7 = (g0.w >> 16)    | (g1.w & 0xffff0000u);
    unsigned int* dst = &Bs[buf][bp_][bh_ * 8];
    uint4 o0; o0.x = w0; o0.y = w1; o0.z = w2; o0.w = w3;
    uint4 o1; o1.x = w4; o1.y = w5; o1.z = w6; o1.w = w7;
    *(uint4*)dst = o0;
    *(uint4*)(dst + 4) = o1;
  };
  auto compute = [&](int buf) {
    bf16x8 af[4], bfr[4];
    #pragma unroll
    for (int m = 0; m < 4; ++m)
      af[m] = *(const bf16x8*)&As[buf][(wr * 64 + m * 16 + (l & 15)) * 32 + ch8];
    const int hl = wc * 64 + (l & 15);
    const int p0 = (l >> 4) * 4;
    #pragma unroll
    for (int n = 0; n < 4; ++n) {
      unsigned int wv[4];
      #pragma unroll
      for (int i = 0; i < 4; ++i) wv[i] = Bs[buf][p0 + i][hl + n * 16];
      bfr[n] = *(bf16x8*)wv;
    }
    __builtin_amdgcn_s_setprio(1);
    #pragma unroll
    for (int m = 0; m < 4; ++m)
      #pragma unroll
      for (int n = 0; n < 4; ++n)
        acc[m][n] = __builtin_amdgcn_mfma_f32_16x16x32_bf16(af[m], bfr[n], acc[m][n], 0, 0, 0);
    __builtin_amdgcn_s_setprio(0);
  };

  // prologue: tiles 0 (buf0/rE) and 1 (buf1/rO)
  uint4 e0, e1, o0, o1;
  Bload(0, e0, e1);    // 2 VMEM
  Agload(0, 0);        // 2 VMEM
  Bload(32, o0, o1);   // 2
  Agload(1, 32);       // 2
  vm_wait<6>();        // B(0) regs in
  Bdswrite(0, e0, e1);
  lgkm0();
  CFENCE(); __builtin_amdgcn_s_barrier(); CFENCE();

  // steady: 14 iters unrolled x2 (static rE/rO sets)
  #pragma unroll 1
  for (int kk = 0; kk < 7; ++kk) {
    const int k = 2 * kk;
    // even iter: tile k (buf0); dswrite tile k+1 (buf1); load tile k+2 (rE)
    vm_wait<4>();                         // A(k) staged (pending: B(k+1),A(k+1))
    compute(0);
    vm_wait<2>();                         // B(k+1) regs in (covered by compute)
    Bdswrite(1, o0, o1);
    lgkm0();
    CFENCE(); __builtin_amdgcn_s_barrier(); CFENCE();
    Bload((k + 2) * 32, e0, e1);
    Agload(0, (k + 2) * 32);
    // odd iter: tile k+1 (buf1); dswrite tile k+2 (buf0); load tile k+3 (rO)
    vm_wait<4>();
    compute(1);
    vm_wait<2>();
    Bdswrite(0, e0, e1);
    lgkm0();
    CFENCE(); __builtin_amdgcn_s_barrier(); CFENCE();
    Bload((k + 3) * 32, o0, o1);
    Agload(1, (k + 3) * 32);
  }
  // epilogue: tiles 14, 15
  vm_wait<4>();
  compute(0);
  vm_wait<0>();
  Bdswrite(1, o0, o1);
  lgkm0();
  CFENCE(); __builtin_amdgcn_s_barrier(); CFENCE();
  compute(1);

  const int cc = l & 15, r4 = (l >> 4) * 4;
  const int row0 = tm * 128 + wr * 64;
  const int col0 = tn * 128 + wc * 64;
  #pragma unroll
  for (int m = 0; m < 4; ++m) {
    #pragma unroll
    for (int n = 0; n < 4; ++n) {
      const int row = row0 + m * 16 + r4;
      const int col = col0 + n * 16 + cc;
      long long base = (long long)bz * 2097152 + (long long)row * 4096 + col;
      #pragma unroll
      for (int j = 0; j < 4; ++j)
        __builtin_nontemporal_store(acc[m][n][j], &C[base + (long long)j * 4096]);
    }
  }
}

// ---------------------------------------------------------------------------
// Row softmax: s [8192 rows][512] f32 -> p_bf [8192][512] bf16
// ---------------------------------------------------------------------------
__global__ __launch_bounds__(256)
void row_softmax_kernel(const float* __restrict__ s, unsigned short* __restrict__ p_bf) {
  __shared__ float red[4], red2[4];
  const float* p = s + (long long)blockIdx.x * 512;
  unsigned short* q = p_bf + (long long)blockIdx.x * 512;
  const int tid = threadIdx.x;
  float v0 = p[tid], v1 = p[tid + 256];
  float m = fmaxf(v0, v1);
  #pragma unroll
  for (int i = 1; i < 64; i <<= 1) m = fmaxf(m, __shfl_xor(m, i));
  if ((tid & 63) == 0) red[tid >> 6] = m;
  __syncthreads();
  m = fmaxf(fmaxf(red[0], red[1]), fmaxf(red[2], red[3]));
  float e0 = __expf(v0 - m), e1 = __expf(v1 - m);
  float sum = e0 + e1;
  #pragma unroll
  for (int i = 1; i < 64; i <<= 1) sum += __shfl_xor(sum, i);
  if ((tid & 63) == 0) red2[tid >> 6] = sum;
  __syncthreads();
  sum = (red2[0] + red2[1]) + (red2[2] + red2[3]);
  float inv = 1.0f / sum;
  q[tid] = f2bf(e0 * inv);
  q[tid + 256] = f2bf(e1 * inv);
}

// ---------------------------------------------------------------------------
// Column softmax (axis 1) + identity fold. grid (16,16), 256 threads:
// 32 d-columns x 8 c-strips of 64 rows, LDS partial reduce.
// ---------------------------------------------------------------------------
__global__ __launch_bounds__(256)
void col_softmax_kernel(const unsigned short* __restrict__ p_bf, unsigned short* __restrict__ a_bf) {
  __shared__ float cs[8][32];
  const int tid = threadIdx.x;
  const int dl = tid & 31;
  const int st = tid >> 5;
  const int d  = blockIdx.x * 32 + dl;
  const long long base = (long long)blockIdx.y * 262144 + d;
  const unsigned short* p = p_bf + base;
  float sum = 0.f;
  #pragma unroll 4
  for (int c = st * 64; c < st * 64 + 64; ++c)
    sum += __expf(bf2f(p[(long long)c * 512]));
  cs[st][dl] = sum;
  __syncthreads();
  if (st == 0) {
    float s = ((cs[0][dl] + cs[1][dl]) + (cs[2][dl] + cs[3][dl]))
            + ((cs[4][dl] + cs[5][dl]) + (cs[6][dl] + cs[7][dl]));
    cs[0][dl] = 1.0f / s;
  }
  __syncthreads();
  const float inv = cs[0][dl];
  unsigned short* q = a_bf + base;
  #pragma unroll 4
  for (int c = st * 64; c < st * 64 + 64; ++c) {
    float v = __expf(bf2f(p[(long long)c * 512])) * inv;
    if (c == d) v += 1.0f;               // residual fold: out = (a+I) @ X
    q[(long long)c * 512] = f2bf(v);
  }
}

// ---------------------------------------------------------------------------
extern "C" void kernel_launch(void* const* d_in, const int* in_sizes, int n_in,
                              void* d_out, int out_size, void* d_ws, size_t ws_size,
                              hipStream_t stream) {
  (void)in_sizes; (void)n_in; (void)out_size; (void)ws_size;
  const float* x = (const float*)d_in[0];   // [16][512][4096]
  const float* W = (const float*)d_in[1];   // [512][512]
  float* out = (float*)d_out;               // [16][512][4096] = 128 MiB
  char* ws = (char*)d_ws;

  // d_out scratch (dead before final gemm overwrites it):
  unsigned short* P    = (unsigned short*)((char*)d_out + 67108864); // [64,84 MiB) bf16 splitK partials
  unsigned short* p_bf = (unsigned short*)((char*)d_out + 88080384); // [84,92 MiB), disjoint from P

  // ws layout (88.5 MiB high water, known-safe):
  unsigned short* x_bf = (unsigned short*)ws;                 // [0, 64 MiB)
  unsigned short* G_bf = (unsigned short*)(ws + 67108864);    // 8 MiB
  float*          s_f  = (float*)(ws + 75497472);             // 16 MiB
  unsigned short* W_bf = (unsigned short*)(ws + 92274688);    // 0.5 MiB
  unsigned short* a_bf = G_bf;   // aliases G_bf (dead after s-gemm)

  // 1) cvt x -> x_bf (pure streaming; xT no longer exists); W -> bf16
  cvt_kernel<<<4096, 256, 0, stream>>>(x, x_bf, 8388608);
  cvt_kernel<<<256, 256, 0, stream>>>(W, W_bf, 65536);

  // 2) G = X X^T: symmetric tiles (10 of 16) x 4 K-splits -> bf16 partials
  gemm_gsym<<<dim3(40, 16), 256, 0, stream>>>(x_bf, P);

  // 3) reduce partials (fp32 sum), write bf16 G (+ mirrored transpose)
  reduce_mirror<<<dim3(10, 16), 256, 0, stream>>>(P, G_bf);

  // 4) s = G W^T (f32). M=N=K=512; W batch-shared.
  gemm_s<<<dim3(64, 16), 256, 0, stream>>>(G_bf, W_bf, s_f);

  // 5) softmax over d (rows, -> bf16 p), then over c (cols) + I -> a (bf16)
  row_softmax_kernel<<<8192, 256, 0, stream>>>(s_f, p_bf);
  col_softmax_kernel<<<dim3(16, 16), 256, 0, stream>>>(p_bf, a_bf);

  // 6) out = (a+I) @ X with fused B-transpose (reads x_bf directly)
  gemm_out<<<dim3(128, 16), 256, 0, stream>>>(a_bf, x_bf, out);
}

// Round 14
// 161.436 us; speedup vs baseline: 1.1425x; 1.0217x over previous
//
#include <hip/hip_runtime.h>

// ---------------------------------------------------------------------------
// WAM_13056700579937: out = softmax_ax1(softmax_ax2((X X^T) W^T)) @ X + X
// B=16, C=512, HW=4096. fp32 in/out; internal bf16 MFMA (16x16x32).
//
// Round 14: row-softmax folded into gemm_s (per-row LSE partials in epilogue);
// col_softmax_v2 combines LSE + single s_f pass with LDS p-tile; cvt merged.
// ---------------------------------------------------------------------------

typedef __attribute__((ext_vector_type(8))) short bf16x8;   // 8 bf16 = 4 VGPR
typedef __attribute__((ext_vector_type(4))) float f32x4;

#define DEVINL __device__ __forceinline__
#define CFENCE() asm volatile("" ::: "memory")

DEVINL unsigned short f2bf(float f) {   // RNE float->bf16 (finite inputs)
  union { float f; unsigned int u; } c; c.f = f;
  unsigned int u = c.u;
  u += 0x7fffu + ((u >> 16) & 1u);
  return (unsigned short)(u >> 16);
}

DEVINL float bf2f(unsigned short h) {
  union { unsigned int u; float f; } c; c.u = ((unsigned int)h) << 16;
  return c.f;
}

DEVINL void gld_lds16(const unsigned short* g, unsigned short* l) {
  __builtin_amdgcn_global_load_lds(
      (const __attribute__((address_space(1))) unsigned int*)g,
      (__attribute__((address_space(3))) unsigned int*)l,
      16 /*bytes, literal*/, 0, 0);
}

template<int N> DEVINL void vm_wait() {
  if constexpr (N == 0)       asm volatile("s_waitcnt vmcnt(0)" ::: "memory");
  else if constexpr (N == 2)  asm volatile("s_waitcnt vmcnt(2)" ::: "memory");
  else if constexpr (N == 4)  asm volatile("s_waitcnt vmcnt(4)" ::: "memory");
  else if constexpr (N == 6)  asm volatile("s_waitcnt vmcnt(6)" ::: "memory");
  else static_assert(N < 0, "unsupported vmcnt");
}

DEVINL void lgkm0() { asm volatile("s_waitcnt lgkmcnt(0)" ::: "memory"); }

DEVINL void sym_tile_decode(int t, int& tm, int& tn) {  // t in [0,10) -> upper 4x4
  if (t < 4)      { tm = 0; tn = t; }
  else if (t < 7) { tm = 1; tn = t - 3; }
  else if (t < 9) { tm = 2; tn = t - 5; }
  else            { tm = 3; tn = 3; }
}

// ---------------------------------------------------------------------------
// cvt fp32 -> bf16, x (8388608 f4) and W (65536 f4) in one launch.
// ---------------------------------------------------------------------------
__global__ __launch_bounds__(256)
void cvt2_kernel(const float* __restrict__ x, unsigned short* __restrict__ x_bf,
                 const float* __restrict__ Wm, unsigned short* __restrict__ W_bf) {
  long long i = (long long)blockIdx.x * 256 + threadIdx.x;
  const long long stride = (long long)gridDim.x * 256;
  for (; i < 8454144; i += stride) {
    const bool isX = (i < 8388608);
    const long long j = isX ? i : (i - 8388608);
    float4 v = isX ? ((const float4*)x)[j] : ((const float4*)Wm)[j];
    unsigned int lo = (unsigned int)f2bf(v.x) | ((unsigned int)f2bf(v.y) << 16);
    unsigned int hi = (unsigned int)f2bf(v.z) | ((unsigned int)f2bf(v.w) << 16);
    uint2 o; o.x = lo; o.y = hi;
    if (isX) ((uint2*)x_bf)[j] = o;
    else     ((uint2*)W_bf)[j] = o;
  }
}

// ---------------------------------------------------------------------------
// G = X X^T, symmetric + split-K, 2-deep counted-vmcnt pipeline. 128^2 tiles.
// Partials written BF16.
// ---------------------------------------------------------------------------
__global__ __launch_bounds__(256)
void gemm_gsym(const unsigned short* __restrict__ X, unsigned short* __restrict__ P) {
  constexpr int HALF = 128 * 32;           // shorts per buffer (8 KB)
  __shared__ unsigned short As[2 * HALF];
  __shared__ unsigned short Bs[2 * HALF];
  const int tid = threadIdx.x;
  const int l   = tid & 63;
  const int w   = tid >> 6;
  const int wr  = w >> 1, wc = w & 1;
  const int b   = blockIdx.y;
  const int t   = blockIdx.x >> 2;
  const int split = blockIdx.x & 3;
  int tm, tn; sym_tile_decode(t, tm, tn);

  const unsigned short* Ab = X + (long long)b * 2097152 + (long long)(tm * 128) * 4096;
  const unsigned short* Bb = X + (long long)b * 2097152 + (long long)(tn * 128) * 4096;

  f32x4 acc[4][4];
  #pragma unroll
  for (int m = 0; m < 4; ++m)
    #pragma unroll
    for (int n = 0; n < 4; ++n) acc[m][n] = (f32x4){0.f, 0.f, 0.f, 0.f};

  const int srow = tid >> 2;
  const int scol = ((tid & 3) ^ ((tid >> 3) & 3)) * 8;
  const int ch8  = (((l >> 4) ^ ((l >> 1) & 3)) * 8);

  auto stage = [&](int buf, int k0) {
    #pragma unroll
    for (int i = 0; i < 2; ++i)
      gld_lds16(Ab + (long long)(i * 64 + srow) * 4096 + k0 + scol, &As[buf * HALF + i * 2048 + tid * 8]);
    #pragma unroll
    for (int i = 0; i < 2; ++i)
      gld_lds16(Bb + (long long)(i * 64 + srow) * 4096 + k0 + scol, &Bs[buf * HALF + i * 2048 + tid * 8]);
  };
  auto compute = [&](int buf) {
    bf16x8 af[4], bfr[4];
    #pragma unroll
    for (int m = 0; m < 4; ++m)
      af[m] = *(const bf16x8*)&As[buf * HALF + (wr * 64 + m * 16 + (l & 15)) * 32 + ch8];
    #pragma unroll
    for (int n = 0; n < 4; ++n)
      bfr[n] = *(const bf16x8*)&Bs[buf * HALF + (wc * 64 + n * 16 + (l & 15)) * 32 + ch8];
    __builtin_amdgcn_s_setprio(1);
    #pragma unroll
    for (int m = 0; m < 4; ++m)
      #pragma unroll
      for (int n = 0; n < 4; ++n)
        acc[m][n] = __builtin_amdgcn_mfma_f32_16x16x32_bf16(af[m], bfr[n], acc[m][n], 0, 0, 0);
    __builtin_amdgcn_s_setprio(0);
  };

  const int k_beg = split * 1024;
  constexpr int NK = 32;
  stage(0, k_beg);
  stage(1, k_beg + 32);
  int ks = k_beg + 64;
  for (int k = 0; k < NK - 2; ++k) {
    vm_wait<4>();
    CFENCE(); __builtin_amdgcn_s_barrier(); CFENCE();
    compute(k & 1);
    CFENCE(); __builtin_amdgcn_s_barrier(); CFENCE();
    stage(k & 1, ks); ks += 32;
  }
  vm_wait<4>();
  CFENCE(); __builtin_amdgcn_s_barrier(); CFENCE();
  compute((NK - 2) & 1);
  vm_wait<0>();
  CFENCE(); __builtin_amdgcn_s_barrier(); CFENCE();
  compute((NK - 1) & 1);

  unsigned short* Pt = P + (((long long)b * 10 + t) * 4 + split) * 16384;
  const int cc = l & 15, r4 = (l >> 4) * 4;
  #pragma unroll
  for (int m = 0; m < 4; ++m) {
    #pragma unroll
    for (int n = 0; n < 4; ++n) {
      const int row = wr * 64 + m * 16 + r4;
      const int col = wc * 64 + n * 16 + cc;
      #pragma unroll
      for (int j = 0; j < 4; ++j)
        Pt[(row + j) * 128 + col] = f2bf(acc[m][n][j]);
    }
  }
}

// ---------------------------------------------------------------------------
// Reduce 4 bf16 split-K partials (fp32 sum) -> bf16 G tile; mirror off-diag.
// ---------------------------------------------------------------------------
__global__ __launch_bounds__(256)
void reduce_mirror(const unsigned short* __restrict__ P, unsigned short* __restrict__ G) {
  __shared__ unsigned short T[128 * 129];
  const int tid = threadIdx.x;
  const int b = blockIdx.y;
  const int t = blockIdx.x;
  int tm, tn; sym_tile_decode(t, tm, tn);
  const unsigned short* Pt = P + ((long long)(b * 10 + t) * 4) * 16384;
  unsigned short* Gb = G + (long long)b * 262144;

  #pragma unroll
  for (int e = 0; e < 16; ++e) {
    const int v = e * 256 + tid;            // ushort4 index (4 elems/thread)
    ushort4 s0 = ((const ushort4*)Pt)[v];
    ushort4 s1 = ((const ushort4*)(Pt + 16384))[v];
    ushort4 s2 = ((const ushort4*)(Pt + 32768))[v];
    ushort4 s3 = ((const ushort4*)(Pt + 49152))[v];
    unsigned int h0 = f2bf(bf2f(s0.x) + bf2f(s1.x) + bf2f(s2.x) + bf2f(s3.x));
    unsigned int h1 = f2bf(bf2f(s0.y) + bf2f(s1.y) + bf2f(s2.y) + bf2f(s3.y));
    unsigned int h2 = f2bf(bf2f(s0.z) + bf2f(s1.z) + bf2f(s2.z) + bf2f(s3.z));
    unsigned int h3 = f2bf(bf2f(s0.w) + bf2f(s1.w) + bf2f(s2.w) + bf2f(s3.w));
    const int idx = v * 4;
    const int r = idx >> 7, c = idx & 127;
    unsigned int* gp = (unsigned int*)(Gb + (long long)(tm * 128 + r) * 512 + tn * 128 + c);
    gp[0] = h0 | (h1 << 16);
    gp[1] = h2 | (h3 << 16);
    unsigned short* tp = &T[r * 129 + c];
    tp[0] = (unsigned short)h0; tp[1] = (unsigned short)h1;
    tp[2] = (unsigned short)h2; tp[3] = (unsigned short)h3;
  }
  if (tm != tn) {
    __syncthreads();
    #pragma unroll
    for (int e = 0; e < 16; ++e) {
      const int idx = (e * 256 + tid) * 4;
      const int r = idx >> 7, c = idx & 127;
      unsigned int o0 = T[(c + 0) * 129 + r], o1 = T[(c + 1) * 129 + r];
      unsigned int o2 = T[(c + 2) * 129 + r], o3 = T[(c + 3) * 129 + r];
      unsigned int* gp = (unsigned int*)(Gb + (long long)(tn * 128 + r) * 512 + tm * 128 + c);
      gp[0] = o0 | (o1 << 16);
      gp[1] = o2 | (o3 << 16);
    }
  }
}

// ---------------------------------------------------------------------------
// s-gemm + row-LSE partials: C = A * B^T (s[c][d]), 64^2 tiles.
// Epilogue: per-row (m, l=sum exp(s-m)) over this block's 64 d-cols via
// 4-step shfl_xor (within 16-lane groups) + cross-wc LDS combine.
// stats[b][c][tn] = (m, l)  (float2).
// ---------------------------------------------------------------------------
__global__ __launch_bounds__(256)
void gemm_s(const unsigned short* __restrict__ A, const unsigned short* __restrict__ B,
            float* __restrict__ C, float* __restrict__ stats) {
  constexpr int HALF = 64 * 32;
  __shared__ unsigned short As[2 * HALF];
  __shared__ unsigned short Bs[2 * HALF];
  __shared__ float sm[2][64], sl[2][64];

  const int tid = threadIdx.x;
  const int l   = tid & 63;
  const int w   = tid >> 6;
  const int wr  = w >> 1, wc = w & 1;
  const int bz  = blockIdx.y;
  const int tm  = blockIdx.x >> 3;
  const int tn  = blockIdx.x & 7;

  const unsigned short* Ab = A + (long long)bz * 262144 + (long long)(tm * 64) * 512;
  const unsigned short* Bb = B + (long long)(tn * 64) * 512;

  f32x4 acc[2][2];
  #pragma unroll
  for (int m = 0; m < 2; ++m)
    #pragma unroll
    for (int n = 0; n < 2; ++n) acc[m][n] = (f32x4){0.f, 0.f, 0.f, 0.f};

  const int srow = tid >> 2;
  const int scol = ((tid & 3) ^ ((tid >> 3) & 3)) * 8;
  const int ch8  = (((l >> 4) ^ ((l >> 1) & 3)) * 8);

  auto stage = [&](int buf, int k0) {
    gld_lds16(Ab + (long long)srow * 512 + k0 + scol, &As[buf * HALF + tid * 8]);
    gld_lds16(Bb + (long long)srow * 512 + k0 + scol, &Bs[buf * HALF + tid * 8]);
  };
  auto compute = [&](int buf) {
    bf16x8 af[2], bfr[2];
    #pragma unroll
    for (int m = 0; m < 2; ++m)
      af[m] = *(const bf16x8*)&As[buf * HALF + (wr * 32 + m * 16 + (l & 15)) * 32 + ch8];
    #pragma unroll
    for (int n = 0; n < 2; ++n)
      bfr[n] = *(const bf16x8*)&Bs[buf * HALF + (wc * 32 + n * 16 + (l & 15)) * 32 + ch8];
    __builtin_amdgcn_s_setprio(1);
    #pragma unroll
    for (int m = 0; m < 2; ++m)
      #pragma unroll
      for (int n = 0; n < 2; ++n)
        acc[m][n] = __builtin_amdgcn_mfma_f32_16x16x32_bf16(af[m], bfr[n], acc[m][n], 0, 0, 0);
    __builtin_amdgcn_s_setprio(0);
  };

  stage(0, 0);
  stage(1, 32);
  int ks = 64;
  for (int k = 0; k < 14; ++k) {
    vm_wait<2>();
    CFENCE(); __builtin_amdgcn_s_barrier(); CFENCE();
    compute(k & 1);
    CFENCE(); __builtin_amdgcn_s_barrier(); CFENCE();
    stage(k & 1, ks); ks += 32;
  }
  vm_wait<2>();
  CFENCE(); __builtin_amdgcn_s_barrier(); CFENCE();
  compute(0);
  vm_wait<0>();
  CFENCE(); __builtin_amdgcn_s_barrier(); CFENCE();
  compute(1);

  const int cc = l & 15, r4 = (l >> 4) * 4;
  const int row0 = tm * 64 + wr * 32;
  const int col0 = tn * 64 + wc * 32;
  #pragma unroll
  for (int m = 0; m < 2; ++m) {
    #pragma unroll
    for (int n = 0; n < 2; ++n) {
      const int row = row0 + m * 16 + r4;
      const int col = col0 + n * 16 + cc;
      long long base = (long long)bz * 262144 + (long long)row * 512 + col;
      #pragma unroll
      for (int j = 0; j < 4; ++j)
        C[base + (long long)j * 512] = acc[m][n][j];
    }
  }

  // --- row-LSE partial epilogue (per block: 64 rows x this block's 64 cols) ---
  float mv[2][4], lv[2][4];
  #pragma unroll
  for (int m = 0; m < 2; ++m)
    #pragma unroll
    for (int j = 0; j < 4; ++j) {
      float v0 = acc[m][0][j], v1 = acc[m][1][j];
      float mx = fmaxf(v0, v1);
      mv[m][j] = mx;
      lv[m][j] = __expf(v0 - mx) + __expf(v1 - mx);
    }
  #pragma unroll
  for (int off = 1; off < 16; off <<= 1) {
    #pragma unroll
    for (int m = 0; m < 2; ++m)
      #pragma unroll
      for (int j = 0; j < 4; ++j) {
        float om = __shfl_xor(mv[m][j], off);
        float ol = __shfl_xor(lv[m][j], off);
        float nm = fmaxf(mv[m][j], om);
        lv[m][j] = lv[m][j] * __expf(mv[m][j] - nm) + ol * __expf(om - nm);
        mv[m][j] = nm;
      }
  }
  if ((l & 15) == 0) {
    const int g = l >> 4;
    #pragma unroll
    for (int m = 0; m < 2; ++m)
      #pragma unroll
      for (int j = 0; j < 4; ++j) {
        const int r = wr * 32 + m * 16 + g * 4 + j;
        sm[wc][r] = mv[m][j];
        sl[wc][r] = lv[m][j];
      }
  }
  __syncthreads();
  if (tid < 64) {
    float m0 = sm[0][tid], l0 = sl[0][tid];
    float m1 = sm[1][tid], l1 = sl[1][tid];
    float M = fmaxf(m0, m1);
    float L = l0 * __expf(m0 - M) + l1 * __expf(m1 - M);
    float2 st; st.x = M; st.y = L;
    ((float2*)stats)[((long long)bz * 512 + tm * 64 + tid) * 8 + tn] = st;
  }
}

// ---------------------------------------------------------------------------
// col_softmax_v2: combine LSE partials -> lse[c]; one pass over s_f computing
// p = exp(s - lse_c), t = exp(p) kept in LDS (bf16) while col-summing; second
// pass from LDS writes a = t/colsum (+1 on diagonal). grid (16,16).
// ---------------------------------------------------------------------------
__global__ __launch_bounds__(256)
void col_softmax_v2(const float* __restrict__ s, const float* __restrict__ stats,
                    unsigned short* __restrict__ a_bf) {
  __shared__ float lse[512];
  __shared__ unsigned short pt[512][32];
  __shared__ float cs[8][32];
  const int tid = threadIdx.x;
  const int b   = blockIdx.y;

  // combine 8 partials per row -> lse
  #pragma unroll
  for (int rr = 0; rr < 2; ++rr) {
    const int r = tid + rr * 256;
    const float2* pp = (const float2*)stats + ((long long)b * 512 + r) * 8;
    float M = pp[0].x;
    #pragma unroll
    for (int q = 1; q < 8; ++q) M = fmaxf(M, pp[q].x);
    float Z = 0.f;
    #pragma unroll
    for (int q = 0; q < 8; ++q) Z += pp[q].y * __expf(pp[q].x - M);
    lse[r] = M + __logf(Z);
  }
  __syncthreads();

  const int dl = tid & 31;
  const int st = tid >> 5;
  const int d  = blockIdx.x * 32 + dl;
  const float* sp = s + (long long)b * 262144 + d;
  float sum = 0.f;
  #pragma unroll 4
  for (int c = st * 64; c < st * 64 + 64; ++c) {
    float p = __expf(sp[(long long)c * 512] - lse[c]);
    float t = __expf(p);
    pt[c][dl] = f2bf(t);
    sum += t;
  }
  cs[st][dl] = sum;
  __syncthreads();
  if (st == 0) {
    float tot = ((cs[0][dl] + cs[1][dl]) + (cs[2][dl] + cs[3][dl]))
              + ((cs[4][dl] + cs[5][dl]) + (cs[6][dl] + cs[7][dl]));
    cs[0][dl] = 1.0f / tot;
  }
  __syncthreads();
  const float inv = cs[0][dl];
  unsigned short* q = a_bf + (long long)b * 262144 + d;
  #pragma unroll 4
  for (int c = st * 64; c < st * 64 + 64; ++c) {
    float v = bf2f(pt[c][dl]) * inv;
    if (c == d) v += 1.0f;               // residual fold: out = (a+I) @ X
    q[(long long)c * 512] = f2bf(v);
  }
}

// ---------------------------------------------------------------------------
// out-gemm with FUSED B-transpose (round-13 structure, unchanged).
// ---------------------------------------------------------------------------
__global__ __launch_bounds__(256)
void gemm_out(const unsigned short* __restrict__ A, const unsigned short* __restrict__ X,
              float* __restrict__ C) {
  __shared__ unsigned short As[2][128 * 32];   // 16 KB
  __shared__ unsigned int   Bs[2][16][132];    // 16.5 KB

  const int tid = threadIdx.x;
  const int l   = tid & 63;
  const int w   = tid >> 6;
  const int wr  = w >> 1, wc = w & 1;
  const int bz  = blockIdx.y;
  const int tm  = blockIdx.x >> 5;    // 4 M-tiles (128 c)
  const int tn  = blockIdx.x & 31;    // 32 N-tiles (128 h)

  const unsigned short* Ab = A + (long long)bz * 262144  + (long long)(tm * 128) * 512;
  const unsigned short* Xb = X + (long long)bz * 2097152 + tn * 128;

  f32x4 acc[4][4];
  #pragma unroll
  for (int m = 0; m < 4; ++m)
    #pragma unroll
    for (int n = 0; n < 4; ++n) acc[m][n] = (f32x4){0.f, 0.f, 0.f, 0.f};

  const int srow = tid >> 2;
  const int scol = ((tid & 3) ^ ((tid >> 3) & 3)) * 8;
  const int ch8  = (((l >> 4) ^ ((l >> 1) & 3)) * 8);
  const int bp_  = tid >> 4;          // dpair 0..15
  const int bh_  = tid & 15;          // h-octet 0..15
  const unsigned short* Bsrc = Xb + (long long)(2 * bp_) * 4096 + bh_ * 8;

  auto Agload = [&](int buf, int k0) {
    #pragma unroll
    for (int i = 0; i < 2; ++i)
      gld_lds16(Ab + (long long)(i * 64 + srow) * 512 + k0 + scol, &As[buf][i * 2048 + tid * 8]);
  };
  auto Bload = [&](int k0, uint4& g0, uint4& g1) {
    g0 = *(const uint4*)(Bsrc + (long long)k0 * 4096);
    g1 = *(const uint4*)(Bsrc + (long long)(k0 + 1) * 4096);
  };
  auto Bdswrite = [&](int buf, const uint4& g0, const uint4& g1) {
    unsigned int w0 = (g0.x & 0xffffu) | (g1.x << 16);
    unsigned int w1 = (g0.x >> 16)    | (g1.x & 0xffff0000u);
    unsigned int w2 = (g0.y & 0xffffu) | (g1.y << 16);
    unsigned int w3 = (g0.y >> 16)    | (g1.y & 0xffff0000u);
    unsigned int w4 = (g0.z & 0xffffu) | (g1.z << 16);
    unsigned int w5 = (g0.z >> 16)    | (g1.z & 0xffff0000u);
    unsigned int w6 = (g0.w & 0xffffu) | (g1.w << 16);
    unsigned int w7 = (g0.w >> 16)    | (g1.w & 0xffff0000u);
    unsigned int* dst = &Bs[buf][bp_][bh_ * 8];
    uint4 o0; o0.x = w0; o0.y = w1; o0.z = w2; o0.w = w3;
    uint4 o1; o1.x = w4; o1.y = w5; o1.z = w6; o1.w = w7;
    *(uint4*)dst = o0;
    *(uint4*)(dst + 4) = o1;
  };
  auto compute = [&](int buf) {
    bf16x8 af[4], bfr[4];
    #pragma unroll
    for (int m = 0; m < 4; ++m)
      af[m] = *(const bf16x8*)&As[buf][(wr * 64 + m * 16 + (l & 15)) * 32 + ch8];
    const int hl = wc * 64 + (l & 15);
    const int p0 = (l >> 4) * 4;
    #pragma unroll
    for (int n = 0; n < 4; ++n) {
      unsigned int wv[4];
      #pragma unroll
      for (int i = 0; i < 4; ++i) wv[i] = Bs[buf][p0 + i][hl + n * 16];
      bfr[n] = *(bf16x8*)wv;
    }
    __builtin_amdgcn_s_setprio(1);
    #pragma unroll
    for (int m = 0; m < 4; ++m)
      #pragma unroll
      for (int n = 0; n < 4; ++n)
        acc[m][n] = __builtin_amdgcn_mfma_f32_16x16x32_bf16(af[m], bfr[n], acc[m][n], 0, 0, 0);
    __builtin_amdgcn_s_setprio(0);
  };

  uint4 e0, e1, o0, o1;
  Bload(0, e0, e1);
  Agload(0, 0);
  Bload(32, o0, o1);
  Agload(1, 32);
  vm_wait<6>();
  Bdswrite(0, e0, e1);
  lgkm0();
  CFENCE(); __builtin_amdgcn_s_barrier(); CFENCE();

  #pragma unroll 1
  for (int kk = 0; kk < 7; ++kk) {
    const int k = 2 * kk;
    vm_wait<4>();
    compute(0);
    vm_wait<2>();
    Bdswrite(1, o0, o1);
    lgkm0();
    CFENCE(); __builtin_amdgcn_s_barrier(); CFENCE();
    Bload((k + 2) * 32, e0, e1);
    Agload(0, (k + 2) * 32);
    vm_wait<4>();
    compute(1);
    vm_wait<2>();
    Bdswrite(0, e0, e1);
    lgkm0();
    CFENCE(); __builtin_amdgcn_s_barrier(); CFENCE();
    Bload((k + 3) * 32, o0, o1);
    Agload(1, (k + 3) * 32);
  }
  vm_wait<4>();
  compute(0);
  vm_wait<0>();
  Bdswrite(1, o0, o1);
  lgkm0();
  CFENCE(); __builtin_amdgcn_s_barrier(); CFENCE();
  compute(1);

  const int cc = l & 15, r4 = (l >> 4) * 4;
  const int row0 = tm * 128 + wr * 64;
  const int col0 = tn * 128 + wc * 64;
  #pragma unroll
  for (int m = 0; m < 4; ++m) {
    #pragma unroll
    for (int n = 0; n < 4; ++n) {
      const int row = row0 + m * 16 + r4;
      const int col = col0 + n * 16 + cc;
      long long base = (long long)bz * 2097152 + (long long)row * 4096 + col;
      #pragma unroll
      for (int j = 0; j < 4; ++j)
        __builtin_nontemporal_store(acc[m][n][j], &C[base + (long long)j * 4096]);
    }
  }
}

// ---------------------------------------------------------------------------
extern "C" void kernel_launch(void* const* d_in, const int* in_sizes, int n_in,
                              void* d_out, int out_size, void* d_ws, size_t ws_size,
                              hipStream_t stream) {
  (void)in_sizes; (void)n_in; (void)out_size; (void)ws_size;
  const float* x = (const float*)d_in[0];   // [16][512][4096]
  const float* W = (const float*)d_in[1];   // [512][512]
  float* out = (float*)d_out;               // [16][512][4096] = 128 MiB
  char* ws = (char*)d_ws;

  // d_out scratch (dead before final gemm overwrites it):
  unsigned short* P = (unsigned short*)((char*)d_out + 67108864); // [64,84 MiB) bf16 splitK partials
  float* s_stats    = (float*)((char*)d_out + 67108864);          // reuses P space (P dead after reduce_mirror)

  // ws layout (88.5 MiB high water, known-safe):
  unsigned short* x_bf = (unsigned short*)ws;                 // [0, 64 MiB)
  unsigned short* G_bf = (unsigned short*)(ws + 67108864);    // 8 MiB
  float*          s_f  = (float*)(ws + 75497472);             // 16 MiB
  unsigned short* W_bf = (unsigned short*)(ws + 92274688);    // 0.5 MiB
  unsigned short* a_bf = G_bf;   // aliases G_bf (dead after s-gemm)

  // 1) cvt x -> x_bf and W -> W_bf (single streaming launch)
  cvt2_kernel<<<4096, 256, 0, stream>>>(x, x_bf, W, W_bf);

  // 2) G = X X^T: symmetric tiles (10 of 16) x 4 K-splits -> bf16 partials
  gemm_gsym<<<dim3(40, 16), 256, 0, stream>>>(x_bf, P);

  // 3) reduce partials (fp32 sum), write bf16 G (+ mirrored transpose)
  reduce_mirror<<<dim3(10, 16), 256, 0, stream>>>(P, G_bf);

  // 4) s = G W^T (f32) + per-row LSE partials (row-softmax fused)
  gemm_s<<<dim3(64, 16), 256, 0, stream>>>(G_bf, W_bf, s_f, s_stats);

  // 5) col_softmax_v2: LSE combine + p + col-softmax + identity fold -> a
  col_softmax_v2<<<dim3(16, 16), 256, 0, stream>>>(s_f, s_stats, a_bf);

  // 6) out = (a+I) @ X with fused B-transpose (reads x_bf directly)
  gemm_out<<<dim3(128, 16), 256, 0, stream>>>(a_bf, x_bf, out);
}

// Round 15
// 158.834 us; speedup vs baseline: 1.1612x; 1.0164x over previous
//
#include <hip/hip_runtime.h>

// ---------------------------------------------------------------------------
// WAM_13056700579937: out = softmax_ax1(softmax_ax2((X X^T) W^T)) @ X + X
// B=16, C=512, HW=4096. fp32 in/out; internal bf16 MFMA (16x16x32).
//
// Round 15: batch-pinned XCD swizzle on gemm_gsym ONLY (r10 showed it was a
// masked win there; the r10 regression was gemm_out's pinning, not gsym's).
// ---------------------------------------------------------------------------

typedef __attribute__((ext_vector_type(8))) short bf16x8;   // 8 bf16 = 4 VGPR
typedef __attribute__((ext_vector_type(4))) float f32x4;

#define DEVINL __device__ __forceinline__
#define CFENCE() asm volatile("" ::: "memory")

DEVINL unsigned short f2bf(float f) {   // RNE float->bf16 (finite inputs)
  union { float f; unsigned int u; } c; c.f = f;
  unsigned int u = c.u;
  u += 0x7fffu + ((u >> 16) & 1u);
  return (unsigned short)(u >> 16);
}

DEVINL float bf2f(unsigned short h) {
  union { unsigned int u; float f; } c; c.u = ((unsigned int)h) << 16;
  return c.f;
}

DEVINL void gld_lds16(const unsigned short* g, unsigned short* l) {
  __builtin_amdgcn_global_load_lds(
      (const __attribute__((address_space(1))) unsigned int*)g,
      (__attribute__((address_space(3))) unsigned int*)l,
      16 /*bytes, literal*/, 0, 0);
}

template<int N> DEVINL void vm_wait() {
  if constexpr (N == 0)       asm volatile("s_waitcnt vmcnt(0)" ::: "memory");
  else if constexpr (N == 2)  asm volatile("s_waitcnt vmcnt(2)" ::: "memory");
  else if constexpr (N == 4)  asm volatile("s_waitcnt vmcnt(4)" ::: "memory");
  else if constexpr (N == 6)  asm volatile("s_waitcnt vmcnt(6)" ::: "memory");
  else static_assert(N < 0, "unsupported vmcnt");
}

DEVINL void lgkm0() { asm volatile("s_waitcnt lgkmcnt(0)" ::: "memory"); }

DEVINL void sym_tile_decode(int t, int& tm, int& tn) {  // t in [0,10) -> upper 4x4
  if (t < 4)      { tm = 0; tn = t; }
  else if (t < 7) { tm = 1; tn = t - 3; }
  else if (t < 9) { tm = 2; tn = t - 5; }
  else            { tm = 3; tn = 3; }
}

// Batch-pinned XCD decode (bijective for grid = 16 * nper, nper blocks/batch;
// launch order round-robins XCDs, so lin&7 == XCD id). Each XCD serves
// batches {2x, 2x+1} temporally -> per-batch 4MB panel stays L2-resident.
DEVINL void xcd_batch_decode(int lin, int nper, int& batch, int& tile) {
  const int xcd  = lin & 7;
  const int slot = lin >> 3;          // [0, 2*nper)
  const int half = (slot >= nper) ? 1 : 0;
  batch = xcd * 2 + half;
  tile  = slot - half * nper;
}

// ---------------------------------------------------------------------------
// cvt fp32 -> bf16, x (8388608 f4) and W (65536 f4) in one launch.
// ---------------------------------------------------------------------------
__global__ __launch_bounds__(256)
void cvt2_kernel(const float* __restrict__ x, unsigned short* __restrict__ x_bf,
                 const float* __restrict__ Wm, unsigned short* __restrict__ W_bf) {
  long long i = (long long)blockIdx.x * 256 + threadIdx.x;
  const long long stride = (long long)gridDim.x * 256;
  for (; i < 8454144; i += stride) {
    const bool isX = (i < 8388608);
    const long long j = isX ? i : (i - 8388608);
    float4 v = isX ? ((const float4*)x)[j] : ((const float4*)Wm)[j];
    unsigned int lo = (unsigned int)f2bf(v.x) | ((unsigned int)f2bf(v.y) << 16);
    unsigned int hi = (unsigned int)f2bf(v.z) | ((unsigned int)f2bf(v.w) << 16);
    uint2 o; o.x = lo; o.y = hi;
    if (isX) ((uint2*)x_bf)[j] = o;
    else     ((uint2*)W_bf)[j] = o;
  }
}

// ---------------------------------------------------------------------------
// G = X X^T, symmetric + split-K, 2-deep counted-vmcnt pipeline. 128^2 tiles.
// 1D grid 640 with batch-pinned XCD swizzle. Partials written BF16.
// ---------------------------------------------------------------------------
__global__ __launch_bounds__(256)
void gemm_gsym(const unsigned short* __restrict__ X, unsigned short* __restrict__ P) {
  constexpr int HALF = 128 * 32;           // shorts per buffer (8 KB)
  __shared__ unsigned short As[2 * HALF];
  __shared__ unsigned short Bs[2 * HALF];
  const int tid = threadIdx.x;
  const int l   = tid & 63;
  const int w   = tid >> 6;
  const int wr  = w >> 1, wc = w & 1;
  int b, tile; xcd_batch_decode(blockIdx.x, 40, b, tile);
  const int t   = tile >> 2;
  const int split = tile & 3;
  int tm, tn; sym_tile_decode(t, tm, tn);

  const unsigned short* Ab = X + (long long)b * 2097152 + (long long)(tm * 128) * 4096;
  const unsigned short* Bb = X + (long long)b * 2097152 + (long long)(tn * 128) * 4096;

  f32x4 acc[4][4];
  #pragma unroll
  for (int m = 0; m < 4; ++m)
    #pragma unroll
    for (int n = 0; n < 4; ++n) acc[m][n] = (f32x4){0.f, 0.f, 0.f, 0.f};

  const int srow = tid >> 2;
  const int scol = ((tid & 3) ^ ((tid >> 3) & 3)) * 8;
  const int ch8  = (((l >> 4) ^ ((l >> 1) & 3)) * 8);

  auto stage = [&](int buf, int k0) {
    #pragma unroll
    for (int i = 0; i < 2; ++i)
      gld_lds16(Ab + (long long)(i * 64 + srow) * 4096 + k0 + scol, &As[buf * HALF + i * 2048 + tid * 8]);
    #pragma unroll
    for (int i = 0; i < 2; ++i)
      gld_lds16(Bb + (long long)(i * 64 + srow) * 4096 + k0 + scol, &Bs[buf * HALF + i * 2048 + tid * 8]);
  };
  auto compute = [&](int buf) {
    bf16x8 af[4], bfr[4];
    #pragma unroll
    for (int m = 0; m < 4; ++m)
      af[m] = *(const bf16x8*)&As[buf * HALF + (wr * 64 + m * 16 + (l & 15)) * 32 + ch8];
    #pragma unroll
    for (int n = 0; n < 4; ++n)
      bfr[n] = *(const bf16x8*)&Bs[buf * HALF + (wc * 64 + n * 16 + (l & 15)) * 32 + ch8];
    __builtin_amdgcn_s_setprio(1);
    #pragma unroll
    for (int m = 0; m < 4; ++m)
      #pragma unroll
      for (int n = 0; n < 4; ++n)
        acc[m][n] = __builtin_amdgcn_mfma_f32_16x16x32_bf16(af[m], bfr[n], acc[m][n], 0, 0, 0);
    __builtin_amdgcn_s_setprio(0);
  };

  const int k_beg = split * 1024;
  constexpr int NK = 32;
  stage(0, k_beg);
  stage(1, k_beg + 32);
  int ks = k_beg + 64;
  for (int k = 0; k < NK - 2; ++k) {
    vm_wait<4>();
    CFENCE(); __builtin_amdgcn_s_barrier(); CFENCE();
    compute(k & 1);
    CFENCE(); __builtin_amdgcn_s_barrier(); CFENCE();
    stage(k & 1, ks); ks += 32;
  }
  vm_wait<4>();
  CFENCE(); __builtin_amdgcn_s_barrier(); CFENCE();
  compute((NK - 2) & 1);
  vm_wait<0>();
  CFENCE(); __builtin_amdgcn_s_barrier(); CFENCE();
  compute((NK - 1) & 1);

  unsigned short* Pt = P + (((long long)b * 10 + t) * 4 + split) * 16384;
  const int cc = l & 15, r4 = (l >> 4) * 4;
  #pragma unroll
  for (int m = 0; m < 4; ++m) {
    #pragma unroll
    for (int n = 0; n < 4; ++n) {
      const int row = wr * 64 + m * 16 + r4;
      const int col = wc * 64 + n * 16 + cc;
      #pragma unroll
      for (int j = 0; j < 4; ++j)
        Pt[(row + j) * 128 + col] = f2bf(acc[m][n][j]);
    }
  }
}

// ---------------------------------------------------------------------------
// Reduce 4 bf16 split-K partials (fp32 sum) -> bf16 G tile; mirror off-diag.
// ---------------------------------------------------------------------------
__global__ __launch_bounds__(256)
void reduce_mirror(const unsigned short* __restrict__ P, unsigned short* __restrict__ G) {
  __shared__ unsigned short T[128 * 129];
  const int tid = threadIdx.x;
  const int b = blockIdx.y;
  const int t = blockIdx.x;
  int tm, tn; sym_tile_decode(t, tm, tn);
  const unsigned short* Pt = P + ((long long)(b * 10 + t) * 4) * 16384;
  unsigned short* Gb = G + (long long)b * 262144;

  #pragma unroll
  for (int e = 0; e < 16; ++e) {
    const int v = e * 256 + tid;            // ushort4 index (4 elems/thread)
    ushort4 s0 = ((const ushort4*)Pt)[v];
    ushort4 s1 = ((const ushort4*)(Pt + 16384))[v];
    ushort4 s2 = ((const ushort4*)(Pt + 32768))[v];
    ushort4 s3 = ((const ushort4*)(Pt + 49152))[v];
    unsigned int h0 = f2bf(bf2f(s0.x) + bf2f(s1.x) + bf2f(s2.x) + bf2f(s3.x));
    unsigned int h1 = f2bf(bf2f(s0.y) + bf2f(s1.y) + bf2f(s2.y) + bf2f(s3.y));
    unsigned int h2 = f2bf(bf2f(s0.z) + bf2f(s1.z) + bf2f(s2.z) + bf2f(s3.z));
    unsigned int h3 = f2bf(bf2f(s0.w) + bf2f(s1.w) + bf2f(s2.w) + bf2f(s3.w));
    const int idx = v * 4;
    const int r = idx >> 7, c = idx & 127;
    unsigned int* gp = (unsigned int*)(Gb + (long long)(tm * 128 + r) * 512 + tn * 128 + c);
    gp[0] = h0 | (h1 << 16);
    gp[1] = h2 | (h3 << 16);
    unsigned short* tp = &T[r * 129 + c];
    tp[0] = (unsigned short)h0; tp[1] = (unsigned short)h1;
    tp[2] = (unsigned short)h2; tp[3] = (unsigned short)h3;
  }
  if (tm != tn) {
    __syncthreads();
    #pragma unroll
    for (int e = 0; e < 16; ++e) {
      const int idx = (e * 256 + tid) * 4;
      const int r = idx >> 7, c = idx & 127;
      unsigned int o0 = T[(c + 0) * 129 + r], o1 = T[(c + 1) * 129 + r];
      unsigned int o2 = T[(c + 2) * 129 + r], o3 = T[(c + 3) * 129 + r];
      unsigned int* gp = (unsigned int*)(Gb + (long long)(tn * 128 + r) * 512 + tm * 128 + c);
      gp[0] = o0 | (o1 << 16);
      gp[1] = o2 | (o3 << 16);
    }
  }
}

// ---------------------------------------------------------------------------
// s-gemm + row-LSE partials: C = A * B^T (s[c][d]), 64^2 tiles.
// stats[b][c][tn] = (m, l) per 64-col block (float2).
// ---------------------------------------------------------------------------
__global__ __launch_bounds__(256)
void gemm_s(const unsigned short* __restrict__ A, const unsigned short* __restrict__ B,
            float* __restrict__ C, float* __restrict__ stats) {
  constexpr int HALF = 64 * 32;
  __shared__ unsigned short As[2 * HALF];
  __shared__ unsigned short Bs[2 * HALF];
  __shared__ float sm[2][64], sl[2][64];

  const int tid = threadIdx.x;
  const int l   = tid & 63;
  const int w   = tid >> 6;
  const int wr  = w >> 1, wc = w & 1;
  const int bz  = blockIdx.y;
  const int tm  = blockIdx.x >> 3;
  const int tn  = blockIdx.x & 7;

  const unsigned short* Ab = A + (long long)bz * 262144 + (long long)(tm * 64) * 512;
  const unsigned short* Bb = B + (long long)(tn * 64) * 512;

  f32x4 acc[2][2];
  #pragma unroll
  for (int m = 0; m < 2; ++m)
    #pragma unroll
    for (int n = 0; n < 2; ++n) acc[m][n] = (f32x4){0.f, 0.f, 0.f, 0.f};

  const int srow = tid >> 2;
  const int scol = ((tid & 3) ^ ((tid >> 3) & 3)) * 8;
  const int ch8  = (((l >> 4) ^ ((l >> 1) & 3)) * 8);

  auto stage = [&](int buf, int k0) {
    gld_lds16(Ab + (long long)srow * 512 + k0 + scol, &As[buf * HALF + tid * 8]);
    gld_lds16(Bb + (long long)srow * 512 + k0 + scol, &Bs[buf * HALF + tid * 8]);
  };
  auto compute = [&](int buf) {
    bf16x8 af[2], bfr[2];
    #pragma unroll
    for (int m = 0; m < 2; ++m)
      af[m] = *(const bf16x8*)&As[buf * HALF + (wr * 32 + m * 16 + (l & 15)) * 32 + ch8];
    #pragma unroll
    for (int n = 0; n < 2; ++n)
      bfr[n] = *(const bf16x8*)&Bs[buf * HALF + (wc * 32 + n * 16 + (l & 15)) * 32 + ch8];
    __builtin_amdgcn_s_setprio(1);
    #pragma unroll
    for (int m = 0; m < 2; ++m)
      #pragma unroll
      for (int n = 0; n < 2; ++n)
        acc[m][n] = __builtin_amdgcn_mfma_f32_16x16x32_bf16(af[m], bfr[n], acc[m][n], 0, 0, 0);
    __builtin_amdgcn_s_setprio(0);
  };

  stage(0, 0);
  stage(1, 32);
  int ks = 64;
  for (int k = 0; k < 14; ++k) {
    vm_wait<2>();
    CFENCE(); __builtin_amdgcn_s_barrier(); CFENCE();
    compute(k & 1);
    CFENCE(); __builtin_amdgcn_s_barrier(); CFENCE();
    stage(k & 1, ks); ks += 32;
  }
  vm_wait<2>();
  CFENCE(); __builtin_amdgcn_s_barrier(); CFENCE();
  compute(0);
  vm_wait<0>();
  CFENCE(); __builtin_amdgcn_s_barrier(); CFENCE();
  compute(1);

  const int cc = l & 15, r4 = (l >> 4) * 4;
  const int row0 = tm * 64 + wr * 32;
  const int col0 = tn * 64 + wc * 32;
  #pragma unroll
  for (int m = 0; m < 2; ++m) {
    #pragma unroll
    for (int n = 0; n < 2; ++n) {
      const int row = row0 + m * 16 + r4;
      const int col = col0 + n * 16 + cc;
      long long base = (long long)bz * 262144 + (long long)row * 512 + col;
      #pragma unroll
      for (int j = 0; j < 4; ++j)
        C[base + (long long)j * 512] = acc[m][n][j];
    }
  }

  // --- row-LSE partial epilogue ---
  float mv[2][4], lv[2][4];
  #pragma unroll
  for (int m = 0; m < 2; ++m)
    #pragma unroll
    for (int j = 0; j < 4; ++j) {
      float v0 = acc[m][0][j], v1 = acc[m][1][j];
      float mx = fmaxf(v0, v1);
      mv[m][j] = mx;
      lv[m][j] = __expf(v0 - mx) + __expf(v1 - mx);
    }
  #pragma unroll
  for (int off = 1; off < 16; off <<= 1) {
    #pragma unroll
    for (int m = 0; m < 2; ++m)
      #pragma unroll
      for (int j = 0; j < 4; ++j) {
        float om = __shfl_xor(mv[m][j], off);
        float ol = __shfl_xor(lv[m][j], off);
        float nm = fmaxf(mv[m][j], om);
        lv[m][j] = lv[m][j] * __expf(mv[m][j] - nm) + ol * __expf(om - nm);
        mv[m][j] = nm;
      }
  }
  if ((l & 15) == 0) {
    const int g = l >> 4;
    #pragma unroll
    for (int m = 0; m < 2; ++m)
      #pragma unroll
      for (int j = 0; j < 4; ++j) {
        const int r = wr * 32 + m * 16 + g * 4 + j;
        sm[wc][r] = mv[m][j];
        sl[wc][r] = lv[m][j];
      }
  }
  __syncthreads();
  if (tid < 64) {
    float m0 = sm[0][tid], l0 = sl[0][tid];
    float m1 = sm[1][tid], l1 = sl[1][tid];
    float M = fmaxf(m0, m1);
    float L = l0 * __expf(m0 - M) + l1 * __expf(m1 - M);
    float2 st; st.x = M; st.y = L;
    ((float2*)stats)[((long long)bz * 512 + tm * 64 + tid) * 8 + tn] = st;
  }
}

// ---------------------------------------------------------------------------
// col_softmax_v2: combine LSE partials -> lse[c]; one s_f pass computing
// t = exp(exp(s-lse)) kept in LDS bf16 while col-summing; write a = t/sum (+I).
// ---------------------------------------------------------------------------
__global__ __launch_bounds__(256)
void col_softmax_v2(const float* __restrict__ s, const float* __restrict__ stats,
                    unsigned short* __restrict__ a_bf) {
  __shared__ float lse[512];
  __shared__ unsigned short pt[512][32];
  __shared__ float cs[8][32];
  const int tid = threadIdx.x;
  const int b   = blockIdx.y;

  #pragma unroll
  for (int rr = 0; rr < 2; ++rr) {
    const int r = tid + rr * 256;
    const float2* pp = (const float2*)stats + ((long long)b * 512 + r) * 8;
    float M = pp[0].x;
    #pragma unroll
    for (int q = 1; q < 8; ++q) M = fmaxf(M, pp[q].x);
    float Z = 0.f;
    #pragma unroll
    for (int q = 0; q < 8; ++q) Z += pp[q].y * __expf(pp[q].x - M);
    lse[r] = M + __logf(Z);
  }
  __syncthreads();

  const int dl = tid & 31;
  const int st = tid >> 5;
  const int d  = blockIdx.x * 32 + dl;
  const float* sp = s + (long long)b * 262144 + d;
  float sum = 0.f;
  #pragma unroll 4
  for (int c = st * 64; c < st * 64 + 64; ++c) {
    float p = __expf(sp[(long long)c * 512] - lse[c]);
    float t = __expf(p);
    pt[c][dl] = f2bf(t);
    sum += t;
  }
  cs[st][dl] = sum;
  __syncthreads();
  if (st == 0) {
    float tot = ((cs[0][dl] + cs[1][dl]) + (cs[2][dl] + cs[3][dl]))
              + ((cs[4][dl] + cs[5][dl]) + (cs[6][dl] + cs[7][dl]));
    cs[0][dl] = 1.0f / tot;
  }
  __syncthreads();
  const float inv = cs[0][dl];
  unsigned short* q = a_bf + (long long)b * 262144 + d;
  #pragma unroll 4
  for (int c = st * 64; c < st * 64 + 64; ++c) {
    float v = bf2f(pt[c][dl]) * inv;
    if (c == d) v += 1.0f;               // residual fold: out = (a+I) @ X
    q[(long long)c * 512] = f2bf(v);
  }
}

// ---------------------------------------------------------------------------
// out-gemm with FUSED B-transpose (round-13 structure, unchanged).
// ---------------------------------------------------------------------------
__global__ __launch_bounds__(256)
void gemm_out(const unsigned short* __restrict__ A, const unsigned short* __restrict__ X,
              float* __restrict__ C) {
  __shared__ unsigned short As[2][128 * 32];   // 16 KB
  __shared__ unsigned int   Bs[2][16][132];    // 16.5 KB

  const int tid = threadIdx.x;
  const int l   = tid & 63;
  const int w   = tid >> 6;
  const int wr  = w >> 1, wc = w & 1;
  const int bz  = blockIdx.y;
  const int tm  = blockIdx.x >> 5;    // 4 M-tiles (128 c)
  const int tn  = blockIdx.x & 31;    // 32 N-tiles (128 h)

  const unsigned short* Ab = A + (long long)bz * 262144  + (long long)(tm * 128) * 512;
  const unsigned short* Xb = X + (long long)bz * 2097152 + tn * 128;

  f32x4 acc[4][4];
  #pragma unroll
  for (int m = 0; m < 4; ++m)
    #pragma unroll
    for (int n = 0; n < 4; ++n) acc[m][n] = (f32x4){0.f, 0.f, 0.f, 0.f};

  const int srow = tid >> 2;
  const int scol = ((tid & 3) ^ ((tid >> 3) & 3)) * 8;
  const int ch8  = (((l >> 4) ^ ((l >> 1) & 3)) * 8);
  const int bp_  = tid >> 4;          // dpair 0..15
  const int bh_  = tid & 15;          // h-octet 0..15
  const unsigned short* Bsrc = Xb + (long long)(2 * bp_) * 4096 + bh_ * 8;

  auto Agload = [&](int buf, int k0) {
    #pragma unroll
    for (int i = 0; i < 2; ++i)
      gld_lds16(Ab + (long long)(i * 64 + srow) * 512 + k0 + scol, &As[buf][i * 2048 + tid * 8]);
  };
  auto Bload = [&](int k0, uint4& g0, uint4& g1) {
    g0 = *(const uint4*)(Bsrc + (long long)k0 * 4096);
    g1 = *(const uint4*)(Bsrc + (long long)(k0 + 1) * 4096);
  };
  auto Bdswrite = [&](int buf, const uint4& g0, const uint4& g1) {
    unsigned int w0 = (g0.x & 0xffffu) | (g1.x << 16);
    unsigned int w1 = (g0.x >> 16)    | (g1.x & 0xffff0000u);
    unsigned int w2 = (g0.y & 0xffffu) | (g1.y << 16);
    unsigned int w3 = (g0.y >> 16)    | (g1.y & 0xffff0000u);
    unsigned int w4 = (g0.z & 0xffffu) | (g1.z << 16);
    unsigned int w5 = (g0.z >> 16)    | (g1.z & 0xffff0000u);
    unsigned int w6 = (g0.w & 0xffffu) | (g1.w << 16);
    unsigned int w7 = (g0.w >> 16)    | (g1.w & 0xffff0000u);
    unsigned int* dst = &Bs[buf][bp_][bh_ * 8];
    uint4 o0; o0.x = w0; o0.y = w1; o0.z = w2; o0.w = w3;
    uint4 o1; o1.x = w4; o1.y = w5; o1.z = w6; o1.w = w7;
    *(uint4*)dst = o0;
    *(uint4*)(dst + 4) = o1;
  };
  auto compute = [&](int buf) {
    bf16x8 af[4], bfr[4];
    #pragma unroll
    for (int m = 0; m < 4; ++m)
      af[m] = *(const bf16x8*)&As[buf][(wr * 64 + m * 16 + (l & 15)) * 32 + ch8];
    const int hl = wc * 64 + (l & 15);
    const int p0 = (l >> 4) * 4;
    #pragma unroll
    for (int n = 0; n < 4; ++n) {
      unsigned int wv[4];
      #pragma unroll
      for (int i = 0; i < 4; ++i) wv[i] = Bs[buf][p0 + i][hl + n * 16];
      bfr[n] = *(bf16x8*)wv;
    }
    __builtin_amdgcn_s_setprio(1);
    #pragma unroll
    for (int m = 0; m < 4; ++m)
      #pragma unroll
      for (int n = 0; n < 4; ++n)
        acc[m][n] = __builtin_amdgcn_mfma_f32_16x16x32_bf16(af[m], bfr[n], acc[m][n], 0, 0, 0);
    __builtin_amdgcn_s_setprio(0);
  };

  uint4 e0, e1, o0, o1;
  Bload(0, e0, e1);
  Agload(0, 0);
  Bload(32, o0, o1);
  Agload(1, 32);
  vm_wait<6>();
  Bdswrite(0, e0, e1);
  lgkm0();
  CFENCE(); __builtin_amdgcn_s_barrier(); CFENCE();

  #pragma unroll 1
  for (int kk = 0; kk < 7; ++kk) {
    const int k = 2 * kk;
    vm_wait<4>();
    compute(0);
    vm_wait<2>();
    Bdswrite(1, o0, o1);
    lgkm0();
    CFENCE(); __builtin_amdgcn_s_barrier(); CFENCE();
    Bload((k + 2) * 32, e0, e1);
    Agload(0, (k + 2) * 32);
    vm_wait<4>();
    compute(1);
    vm_wait<2>();
    Bdswrite(0, e0, e1);
    lgkm0();
    CFENCE(); __builtin_amdgcn_s_barrier(); CFENCE();
    Bload((k + 3) * 32, o0, o1);
    Agload(1, (k + 3) * 32);
  }
  vm_wait<4>();
  compute(0);
  vm_wait<0>();
  Bdswrite(1, o0, o1);
  lgkm0();
  CFENCE(); __builtin_amdgcn_s_barrier(); CFENCE();
  compute(1);

  const int cc = l & 15, r4 = (l >> 4) * 4;
  const int row0 = tm * 128 + wr * 64;
  const int col0 = tn * 128 + wc * 64;
  #pragma unroll
  for (int m = 0; m < 4; ++m) {
    #pragma unroll
    for (int n = 0; n < 4; ++n) {
      const int row = row0 + m * 16 + r4;
      const int col = col0 + n * 16 + cc;
      long long base = (long long)bz * 2097152 + (long long)row * 4096 + col;
      #pragma unroll
      for (int j = 0; j < 4; ++j)
        __builtin_nontemporal_store(acc[m][n][j], &C[base + (long long)j * 4096]);
    }
  }
}

// ---------------------------------------------------------------------------
extern "C" void kernel_launch(void* const* d_in, const int* in_sizes, int n_in,
                              void* d_out, int out_size, void* d_ws, size_t ws_size,
                              hipStream_t stream) {
  (void)in_sizes; (void)n_in; (void)out_size; (void)ws_size;
  const float* x = (const float*)d_in[0];   // [16][512][4096]
  const float* W = (const float*)d_in[1];   // [512][512]
  float* out = (float*)d_out;               // [16][512][4096] = 128 MiB
  char* ws = (char*)d_ws;

  // d_out scratch (dead before final gemm overwrites it):
  unsigned short* P = (unsigned short*)((char*)d_out + 67108864); // [64,84 MiB) bf16 splitK partials
  float* s_stats    = (float*)((char*)d_out + 67108864);          // reuses P space (P dead after reduce_mirror)

  // ws layout (88.5 MiB high water, known-safe):
  unsigned short* x_bf = (unsigned short*)ws;                 // [0, 64 MiB)
  unsigned short* G_bf = (unsigned short*)(ws + 67108864);    // 8 MiB
  float*          s_f  = (float*)(ws + 75497472);             // 16 MiB
  unsigned short* W_bf = (unsigned short*)(ws + 92274688);    // 0.5 MiB
  unsigned short* a_bf = G_bf;   // aliases G_bf (dead after s-gemm)

  // 1) cvt x -> x_bf and W -> W_bf (single streaming launch)
  cvt2_kernel<<<4096, 256, 0, stream>>>(x, x_bf, W, W_bf);

  // 2) G = X X^T: symmetric tiles x 4 K-splits, batch-pinned XCD swizzle
  gemm_gsym<<<640, 256, 0, stream>>>(x_bf, P);

  // 3) reduce partials (fp32 sum), write bf16 G (+ mirrored transpose)
  reduce_mirror<<<dim3(10, 16), 256, 0, stream>>>(P, G_bf);

  // 4) s = G W^T (f32) + per-row LSE partials (row-softmax fused)
  gemm_s<<<dim3(64, 16), 256, 0, stream>>>(G_bf, W_bf, s_f, s_stats);

  // 5) col_softmax_v2: LSE combine + p + col-softmax + identity fold -> a
  col_softmax_v2<<<dim3(16, 16), 256, 0, stream>>>(s_f, s_stats, a_bf);

  // 6) out = (a+I) @ X with fused B-transpose (reads x_bf directly)
  gemm_out<<<dim3(128, 16), 256, 0, stream>>>(a_bf, x_bf, out);
}

// Round 16
// 158.531 us; speedup vs baseline: 1.1635x; 1.0019x over previous
//
#include <hip/hip_runtime.h>

// ---------------------------------------------------------------------------
// WAM_13056700579937: out = softmax_ax1(softmax_ax2((X X^T) W^T)) @ X + X
// B=16, C=512, HW=4096. fp32 in/out; internal bf16 MFMA (16x16x32).
//
// Round 16: gemm_out race fix — A-tile consume now vm_wait -> s_barrier ->
// compute (gsym-proven pattern, 2 barriers/K-step). Cross-wave gload_lds
// retirement was previously unordered before reads (timing-masked race).
// ---------------------------------------------------------------------------

typedef __attribute__((ext_vector_type(8))) short bf16x8;   // 8 bf16 = 4 VGPR
typedef __attribute__((ext_vector_type(4))) float f32x4;

#define DEVINL __device__ __forceinline__
#define CFENCE() asm volatile("" ::: "memory")

DEVINL unsigned short f2bf(float f) {   // RNE float->bf16 (finite inputs)
  union { float f; unsigned int u; } c; c.f = f;
  unsigned int u = c.u;
  u += 0x7fffu + ((u >> 16) & 1u);
  return (unsigned short)(u >> 16);
}

DEVINL float bf2f(unsigned short h) {
  union { unsigned int u; float f; } c; c.u = ((unsigned int)h) << 16;
  return c.f;
}

DEVINL void gld_lds16(const unsigned short* g, unsigned short* l) {
  __builtin_amdgcn_global_load_lds(
      (const __attribute__((address_space(1))) unsigned int*)g,
      (__attribute__((address_space(3))) unsigned int*)l,
      16 /*bytes, literal*/, 0, 0);
}

template<int N> DEVINL void vm_wait() {
  if constexpr (N == 0)       asm volatile("s_waitcnt vmcnt(0)" ::: "memory");
  else if constexpr (N == 2)  asm volatile("s_waitcnt vmcnt(2)" ::: "memory");
  else if constexpr (N == 4)  asm volatile("s_waitcnt vmcnt(4)" ::: "memory");
  else if constexpr (N == 6)  asm volatile("s_waitcnt vmcnt(6)" ::: "memory");
  else static_assert(N < 0, "unsupported vmcnt");
}

DEVINL void lgkm0() { asm volatile("s_waitcnt lgkmcnt(0)" ::: "memory"); }

DEVINL void sym_tile_decode(int t, int& tm, int& tn) {  // t in [0,10) -> upper 4x4
  if (t < 4)      { tm = 0; tn = t; }
  else if (t < 7) { tm = 1; tn = t - 3; }
  else if (t < 9) { tm = 2; tn = t - 5; }
  else            { tm = 3; tn = 3; }
}

// Batch-pinned XCD decode (bijective for grid = 16 * nper; lin&7 == XCD id).
DEVINL void xcd_batch_decode(int lin, int nper, int& batch, int& tile) {
  const int xcd  = lin & 7;
  const int slot = lin >> 3;          // [0, 2*nper)
  const int half = (slot >= nper) ? 1 : 0;
  batch = xcd * 2 + half;
  tile  = slot - half * nper;
}

// ---------------------------------------------------------------------------
// cvt fp32 -> bf16, x (8388608 f4) and W (65536 f4) in one launch.
// ---------------------------------------------------------------------------
__global__ __launch_bounds__(256)
void cvt2_kernel(const float* __restrict__ x, unsigned short* __restrict__ x_bf,
                 const float* __restrict__ Wm, unsigned short* __restrict__ W_bf) {
  long long i = (long long)blockIdx.x * 256 + threadIdx.x;
  const long long stride = (long long)gridDim.x * 256;
  for (; i < 8454144; i += stride) {
    const bool isX = (i < 8388608);
    const long long j = isX ? i : (i - 8388608);
    float4 v = isX ? ((const float4*)x)[j] : ((const float4*)Wm)[j];
    unsigned int lo = (unsigned int)f2bf(v.x) | ((unsigned int)f2bf(v.y) << 16);
    unsigned int hi = (unsigned int)f2bf(v.z) | ((unsigned int)f2bf(v.w) << 16);
    uint2 o; o.x = lo; o.y = hi;
    if (isX) ((uint2*)x_bf)[j] = o;
    else     ((uint2*)W_bf)[j] = o;
  }
}

// ---------------------------------------------------------------------------
// G = X X^T, symmetric + split-K, 2-deep counted-vmcnt pipeline. 128^2 tiles.
// 1D grid 640 with batch-pinned XCD swizzle. Partials written BF16.
// ---------------------------------------------------------------------------
__global__ __launch_bounds__(256)
void gemm_gsym(const unsigned short* __restrict__ X, unsigned short* __restrict__ P) {
  constexpr int HALF = 128 * 32;           // shorts per buffer (8 KB)
  __shared__ unsigned short As[2 * HALF];
  __shared__ unsigned short Bs[2 * HALF];
  const int tid = threadIdx.x;
  const int l   = tid & 63;
  const int w   = tid >> 6;
  const int wr  = w >> 1, wc = w & 1;
  int b, tile; xcd_batch_decode(blockIdx.x, 40, b, tile);
  const int t   = tile >> 2;
  const int split = tile & 3;
  int tm, tn; sym_tile_decode(t, tm, tn);

  const unsigned short* Ab = X + (long long)b * 2097152 + (long long)(tm * 128) * 4096;
  const unsigned short* Bb = X + (long long)b * 2097152 + (long long)(tn * 128) * 4096;

  f32x4 acc[4][4];
  #pragma unroll
  for (int m = 0; m < 4; ++m)
    #pragma unroll
    for (int n = 0; n < 4; ++n) acc[m][n] = (f32x4){0.f, 0.f, 0.f, 0.f};

  const int srow = tid >> 2;
  const int scol = ((tid & 3) ^ ((tid >> 3) & 3)) * 8;
  const int ch8  = (((l >> 4) ^ ((l >> 1) & 3)) * 8);

  auto stage = [&](int buf, int k0) {
    #pragma unroll
    for (int i = 0; i < 2; ++i)
      gld_lds16(Ab + (long long)(i * 64 + srow) * 4096 + k0 + scol, &As[buf * HALF + i * 2048 + tid * 8]);
    #pragma unroll
    for (int i = 0; i < 2; ++i)
      gld_lds16(Bb + (long long)(i * 64 + srow) * 4096 + k0 + scol, &Bs[buf * HALF + i * 2048 + tid * 8]);
  };
  auto compute = [&](int buf) {
    bf16x8 af[4], bfr[4];
    #pragma unroll
    for (int m = 0; m < 4; ++m)
      af[m] = *(const bf16x8*)&As[buf * HALF + (wr * 64 + m * 16 + (l & 15)) * 32 + ch8];
    #pragma unroll
    for (int n = 0; n < 4; ++n)
      bfr[n] = *(const bf16x8*)&Bs[buf * HALF + (wc * 64 + n * 16 + (l & 15)) * 32 + ch8];
    __builtin_amdgcn_s_setprio(1);
    #pragma unroll
    for (int m = 0; m < 4; ++m)
      #pragma unroll
      for (int n = 0; n < 4; ++n)
        acc[m][n] = __builtin_amdgcn_mfma_f32_16x16x32_bf16(af[m], bfr[n], acc[m][n], 0, 0, 0);
    __builtin_amdgcn_s_setprio(0);
  };

  const int k_beg = split * 1024;
  constexpr int NK = 32;
  stage(0, k_beg);
  stage(1, k_beg + 32);
  int ks = k_beg + 64;
  for (int k = 0; k < NK - 2; ++k) {
    vm_wait<4>();
    CFENCE(); __builtin_amdgcn_s_barrier(); CFENCE();
    compute(k & 1);
    CFENCE(); __builtin_amdgcn_s_barrier(); CFENCE();
    stage(k & 1, ks); ks += 32;
  }
  vm_wait<4>();
  CFENCE(); __builtin_amdgcn_s_barrier(); CFENCE();
  compute((NK - 2) & 1);
  vm_wait<0>();
  CFENCE(); __builtin_amdgcn_s_barrier(); CFENCE();
  compute((NK - 1) & 1);

  unsigned short* Pt = P + (((long long)b * 10 + t) * 4 + split) * 16384;
  const int cc = l & 15, r4 = (l >> 4) * 4;
  #pragma unroll
  for (int m = 0; m < 4; ++m) {
    #pragma unroll
    for (int n = 0; n < 4; ++n) {
      const int row = wr * 64 + m * 16 + r4;
      const int col = wc * 64 + n * 16 + cc;
      #pragma unroll
      for (int j = 0; j < 4; ++j)
        Pt[(row + j) * 128 + col] = f2bf(acc[m][n][j]);
    }
  }
}

// ---------------------------------------------------------------------------
// Reduce 4 bf16 split-K partials (fp32 sum) -> bf16 G tile; mirror off-diag.
// ---------------------------------------------------------------------------
__global__ __launch_bounds__(256)
void reduce_mirror(const unsigned short* __restrict__ P, unsigned short* __restrict__ G) {
  __shared__ unsigned short T[128 * 129];
  const int tid = threadIdx.x;
  const int b = blockIdx.y;
  const int t = blockIdx.x;
  int tm, tn; sym_tile_decode(t, tm, tn);
  const unsigned short* Pt = P + ((long long)(b * 10 + t) * 4) * 16384;
  unsigned short* Gb = G + (long long)b * 262144;

  #pragma unroll
  for (int e = 0; e < 16; ++e) {
    const int v = e * 256 + tid;            // ushort4 index (4 elems/thread)
    ushort4 s0 = ((const ushort4*)Pt)[v];
    ushort4 s1 = ((const ushort4*)(Pt + 16384))[v];
    ushort4 s2 = ((const ushort4*)(Pt + 32768))[v];
    ushort4 s3 = ((const ushort4*)(Pt + 49152))[v];
    unsigned int h0 = f2bf(bf2f(s0.x) + bf2f(s1.x) + bf2f(s2.x) + bf2f(s3.x));
    unsigned int h1 = f2bf(bf2f(s0.y) + bf2f(s1.y) + bf2f(s2.y) + bf2f(s3.y));
    unsigned int h2 = f2bf(bf2f(s0.z) + bf2f(s1.z) + bf2f(s2.z) + bf2f(s3.z));
    unsigned int h3 = f2bf(bf2f(s0.w) + bf2f(s1.w) + bf2f(s2.w) + bf2f(s3.w));
    const int idx = v * 4;
    const int r = idx >> 7, c = idx & 127;
    unsigned int* gp = (unsigned int*)(Gb + (long long)(tm * 128 + r) * 512 + tn * 128 + c);
    gp[0] = h0 | (h1 << 16);
    gp[1] = h2 | (h3 << 16);
    unsigned short* tp = &T[r * 129 + c];
    tp[0] = (unsigned short)h0; tp[1] = (unsigned short)h1;
    tp[2] = (unsigned short)h2; tp[3] = (unsigned short)h3;
  }
  if (tm != tn) {
    __syncthreads();
    #pragma unroll
    for (int e = 0; e < 16; ++e) {
      const int idx = (e * 256 + tid) * 4;
      const int r = idx >> 7, c = idx & 127;
      unsigned int o0 = T[(c + 0) * 129 + r], o1 = T[(c + 1) * 129 + r];
      unsigned int o2 = T[(c + 2) * 129 + r], o3 = T[(c + 3) * 129 + r];
      unsigned int* gp = (unsigned int*)(Gb + (long long)(tn * 128 + r) * 512 + tm * 128 + c);
      gp[0] = o0 | (o1 << 16);
      gp[1] = o2 | (o3 << 16);
    }
  }
}

// ---------------------------------------------------------------------------
// s-gemm + row-LSE partials: C = A * B^T (s[c][d]), 64^2 tiles.
// stats[b][c][tn] = (m, l) per 64-col block (float2).
// ---------------------------------------------------------------------------
__global__ __launch_bounds__(256)
void gemm_s(const unsigned short* __restrict__ A, const unsigned short* __restrict__ B,
            float* __restrict__ C, float* __restrict__ stats) {
  constexpr int HALF = 64 * 32;
  __shared__ unsigned short As[2 * HALF];
  __shared__ unsigned short Bs[2 * HALF];
  __shared__ float sm[2][64], sl[2][64];

  const int tid = threadIdx.x;
  const int l   = tid & 63;
  const int w   = tid >> 6;
  const int wr  = w >> 1, wc = w & 1;
  const int bz  = blockIdx.y;
  const int tm  = blockIdx.x >> 3;
  const int tn  = blockIdx.x & 7;

  const unsigned short* Ab = A + (long long)bz * 262144 + (long long)(tm * 64) * 512;
  const unsigned short* Bb = B + (long long)(tn * 64) * 512;

  f32x4 acc[2][2];
  #pragma unroll
  for (int m = 0; m < 2; ++m)
    #pragma unroll
    for (int n = 0; n < 2; ++n) acc[m][n] = (f32x4){0.f, 0.f, 0.f, 0.f};

  const int srow = tid >> 2;
  const int scol = ((tid & 3) ^ ((tid >> 3) & 3)) * 8;
  const int ch8  = (((l >> 4) ^ ((l >> 1) & 3)) * 8);

  auto stage = [&](int buf, int k0) {
    gld_lds16(Ab + (long long)srow * 512 + k0 + scol, &As[buf * HALF + tid * 8]);
    gld_lds16(Bb + (long long)srow * 512 + k0 + scol, &Bs[buf * HALF + tid * 8]);
  };
  auto compute = [&](int buf) {
    bf16x8 af[2], bfr[2];
    #pragma unroll
    for (int m = 0; m < 2; ++m)
      af[m] = *(const bf16x8*)&As[buf * HALF + (wr * 32 + m * 16 + (l & 15)) * 32 + ch8];
    #pragma unroll
    for (int n = 0; n < 2; ++n)
      bfr[n] = *(const bf16x8*)&Bs[buf * HALF + (wc * 32 + n * 16 + (l & 15)) * 32 + ch8];
    __builtin_amdgcn_s_setprio(1);
    #pragma unroll
    for (int m = 0; m < 2; ++m)
      #pragma unroll
      for (int n = 0; n < 2; ++n)
        acc[m][n] = __builtin_amdgcn_mfma_f32_16x16x32_bf16(af[m], bfr[n], acc[m][n], 0, 0, 0);
    __builtin_amdgcn_s_setprio(0);
  };

  stage(0, 0);
  stage(1, 32);
  int ks = 64;
  for (int k = 0; k < 14; ++k) {
    vm_wait<2>();
    CFENCE(); __builtin_amdgcn_s_barrier(); CFENCE();
    compute(k & 1);
    CFENCE(); __builtin_amdgcn_s_barrier(); CFENCE();
    stage(k & 1, ks); ks += 32;
  }
  vm_wait<2>();
  CFENCE(); __builtin_amdgcn_s_barrier(); CFENCE();
  compute(0);
  vm_wait<0>();
  CFENCE(); __builtin_amdgcn_s_barrier(); CFENCE();
  compute(1);

  const int cc = l & 15, r4 = (l >> 4) * 4;
  const int row0 = tm * 64 + wr * 32;
  const int col0 = tn * 64 + wc * 32;
  #pragma unroll
  for (int m = 0; m < 2; ++m) {
    #pragma unroll
    for (int n = 0; n < 2; ++n) {
      const int row = row0 + m * 16 + r4;
      const int col = col0 + n * 16 + cc;
      long long base = (long long)bz * 262144 + (long long)row * 512 + col;
      #pragma unroll
      for (int j = 0; j < 4; ++j)
        C[base + (long long)j * 512] = acc[m][n][j];
    }
  }

  // --- row-LSE partial epilogue ---
  float mv[2][4], lv[2][4];
  #pragma unroll
  for (int m = 0; m < 2; ++m)
    #pragma unroll
    for (int j = 0; j < 4; ++j) {
      float v0 = acc[m][0][j], v1 = acc[m][1][j];
      float mx = fmaxf(v0, v1);
      mv[m][j] = mx;
      lv[m][j] = __expf(v0 - mx) + __expf(v1 - mx);
    }
  #pragma unroll
  for (int off = 1; off < 16; off <<= 1) {
    #pragma unroll
    for (int m = 0; m < 2; ++m)
      #pragma unroll
      for (int j = 0; j < 4; ++j) {
        float om = __shfl_xor(mv[m][j], off);
        float ol = __shfl_xor(lv[m][j], off);
        float nm = fmaxf(mv[m][j], om);
        lv[m][j] = lv[m][j] * __expf(mv[m][j] - nm) + ol * __expf(om - nm);
        mv[m][j] = nm;
      }
  }
  if ((l & 15) == 0) {
    const int g = l >> 4;
    #pragma unroll
    for (int m = 0; m < 2; ++m)
      #pragma unroll
      for (int j = 0; j < 4; ++j) {
        const int r = wr * 32 + m * 16 + g * 4 + j;
        sm[wc][r] = mv[m][j];
        sl[wc][r] = lv[m][j];
      }
  }
  __syncthreads();
  if (tid < 64) {
    float m0 = sm[0][tid], l0 = sl[0][tid];
    float m1 = sm[1][tid], l1 = sl[1][tid];
    float M = fmaxf(m0, m1);
    float L = l0 * __expf(m0 - M) + l1 * __expf(m1 - M);
    float2 st; st.x = M; st.y = L;
    ((float2*)stats)[((long long)bz * 512 + tm * 64 + tid) * 8 + tn] = st;
  }
}

// ---------------------------------------------------------------------------
// col_softmax_v2: combine LSE partials -> lse[c]; one s_f pass computing
// t = exp(exp(s-lse)) kept in LDS bf16 while col-summing; write a = t/sum (+I).
// ---------------------------------------------------------------------------
__global__ __launch_bounds__(256)
void col_softmax_v2(const float* __restrict__ s, const float* __restrict__ stats,
                    unsigned short* __restrict__ a_bf) {
  __shared__ float lse[512];
  __shared__ unsigned short pt[512][32];
  __shared__ float cs[8][32];
  const int tid = threadIdx.x;
  const int b   = blockIdx.y;

  #pragma unroll
  for (int rr = 0; rr < 2; ++rr) {
    const int r = tid + rr * 256;
    const float2* pp = (const float2*)stats + ((long long)b * 512 + r) * 8;
    float M = pp[0].x;
    #pragma unroll
    for (int q = 1; q < 8; ++q) M = fmaxf(M, pp[q].x);
    float Z = 0.f;
    #pragma unroll
    for (int q = 0; q < 8; ++q) Z += pp[q].y * __expf(pp[q].x - M);
    lse[r] = M + __logf(Z);
  }
  __syncthreads();

  const int dl = tid & 31;
  const int st = tid >> 5;
  const int d  = blockIdx.x * 32 + dl;
  const float* sp = s + (long long)b * 262144 + d;
  float sum = 0.f;
  #pragma unroll 4
  for (int c = st * 64; c < st * 64 + 64; ++c) {
    float p = __expf(sp[(long long)c * 512] - lse[c]);
    float t = __expf(p);
    pt[c][dl] = f2bf(t);
    sum += t;
  }
  cs[st][dl] = sum;
  __syncthreads();
  if (st == 0) {
    float tot = ((cs[0][dl] + cs[1][dl]) + (cs[2][dl] + cs[3][dl]))
              + ((cs[4][dl] + cs[5][dl]) + (cs[6][dl] + cs[7][dl]));
    cs[0][dl] = 1.0f / tot;
  }
  __syncthreads();
  const float inv = cs[0][dl];
  unsigned short* q = a_bf + (long long)b * 262144 + d;
  #pragma unroll 4
  for (int c = st * 64; c < st * 64 + 64; ++c) {
    float v = bf2f(pt[c][dl]) * inv;
    if (c == d) v += 1.0f;               // residual fold: out = (a+I) @ X
    q[(long long)c * 512] = f2bf(v);
  }
}

// ---------------------------------------------------------------------------
// out-gemm with FUSED B-transpose. Race-fixed schedule:
// per K-step: vm_wait<4> (own A(k)) -> s_barrier (ALL waves' A(k) landed,
// Bs published) -> compute -> vm_wait<2> -> Bdswrite(k+1) -> lgkm0 ->
// s_barrier -> issue Bload(k+2)/Agload(k+2).
// ---------------------------------------------------------------------------
__global__ __launch_bounds__(256)
void gemm_out(const unsigned short* __restrict__ A, const unsigned short* __restrict__ X,
              float* __restrict__ C) {
  __shared__ unsigned short As[2][128 * 32];   // 16 KB
  __shared__ unsigned int   Bs[2][16][132];    // 16.5 KB

  const int tid = threadIdx.x;
  const int l   = tid & 63;
  const int w   = tid >> 6;
  const int wr  = w >> 1, wc = w & 1;
  const int bz  = blockIdx.y;
  const int tm  = blockIdx.x >> 5;    // 4 M-tiles (128 c)
  const int tn  = blockIdx.x & 31;    // 32 N-tiles (128 h)

  const unsigned short* Ab = A + (long long)bz * 262144  + (long long)(tm * 128) * 512;
  const unsigned short* Xb = X + (long long)bz * 2097152 + tn * 128;

  f32x4 acc[4][4];
  #pragma unroll
  for (int m = 0; m < 4; ++m)
    #pragma unroll
    for (int n = 0; n < 4; ++n) acc[m][n] = (f32x4){0.f, 0.f, 0.f, 0.f};

  const int srow = tid >> 2;
  const int scol = ((tid & 3) ^ ((tid >> 3) & 3)) * 8;
  const int ch8  = (((l >> 4) ^ ((l >> 1) & 3)) * 8);
  const int bp_  = tid >> 4;          // dpair 0..15
  const int bh_  = tid & 15;          // h-octet 0..15
  const unsigned short* Bsrc = Xb + (long long)(2 * bp_) * 4096 + bh_ * 8;

  auto Agload = [&](int buf, int k0) {
    #pragma unroll
    for (int i = 0; i < 2; ++i)
      gld_lds16(Ab + (long long)(i * 64 + srow) * 512 + k0 + scol, &As[buf][i * 2048 + tid * 8]);
  };
  auto Bload = [&](int k0, uint4& g0, uint4& g1) {
    g0 = *(const uint4*)(Bsrc + (long long)k0 * 4096);
    g1 = *(const uint4*)(Bsrc + (long long)(k0 + 1) * 4096);
  };
  auto Bdswrite = [&](int buf, const uint4& g0, const uint4& g1) {
    unsigned int w0 = (g0.x & 0xffffu) | (g1.x << 16);
    unsigned int w1 = (g0.x >> 16)    | (g1.x & 0xffff0000u);
    unsigned int w2 = (g0.y & 0xffffu) | (g1.y << 16);
    unsigned int w3 = (g0.y >> 16)    | (g1.y & 0xffff0000u);
    unsigned int w4 = (g0.z & 0xffffu) | (g1.z << 16);
    unsigned int w5 = (g0.z >> 16)    | (g1.z & 0xffff0000u);
    unsigned int w6 = (g0.w & 0xffffu) | (g1.w << 16);
    unsigned int w7 = (g0.w >> 16)    | (g1.w & 0xffff0000u);
    unsigned int* dst = &Bs[buf][bp_][bh_ * 8];
    uint4 o0; o0.x = w0; o0.y = w1; o0.z = w2; o0.w = w3;
    uint4 o1; o1.x = w4; o1.y = w5; o1.z = w6; o1.w = w7;
    *(uint4*)dst = o0;
    *(uint4*)(dst + 4) = o1;
  };
  auto compute = [&](int buf) {
    bf16x8 af[4], bfr[4];
    #pragma unroll
    for (int m = 0; m < 4; ++m)
      af[m] = *(const bf16x8*)&As[buf][(wr * 64 + m * 16 + (l & 15)) * 32 + ch8];
    const int hl = wc * 64 + (l & 15);
    const int p0 = (l >> 4) * 4;
    #pragma unroll
    for (int n = 0; n < 4; ++n) {
      unsigned int wv[4];
      #pragma unroll
      for (int i = 0; i < 4; ++i) wv[i] = Bs[buf][p0 + i][hl + n * 16];
      bfr[n] = *(bf16x8*)wv;
    }
    __builtin_amdgcn_s_setprio(1);
    #pragma unroll
    for (int m = 0; m < 4; ++m)
      #pragma unroll
      for (int n = 0; n < 4; ++n)
        acc[m][n] = __builtin_amdgcn_mfma_f32_16x16x32_bf16(af[m], bfr[n], acc[m][n], 0, 0, 0);
    __builtin_amdgcn_s_setprio(0);
  };

  // prologue: tiles 0 (buf0/e-regs) and 1 (buf1/o-regs)
  uint4 e0, e1, o0, o1;
  Bload(0, e0, e1);    // 2 VMEM
  Agload(0, 0);        // 2
  Bload(32, o0, o1);   // 2
  Agload(1, 32);       // 2
  vm_wait<6>();        // B(0) regs in
  Bdswrite(0, e0, e1);
  lgkm0();             // own Bs[0] writes done; published at first loop barrier

  // steady: 14 K-steps, unrolled x2 (static e/o reg sets)
  #pragma unroll 1
  for (int kk = 0; kk < 7; ++kk) {
    const int k = 2 * kk;
    // even: tile k (buf0); write B(k+1) -> Bs[1]; load tile k+2 (e-regs)
    vm_wait<4>();                         // own A(k) retired
    CFENCE(); __builtin_amdgcn_s_barrier(); CFENCE();  // ALL A(k) landed + Bs pub
    compute(0);
    vm_wait<2>();                         // B(k+1) regs in
    Bdswrite(1, o0, o1);
    lgkm0();
    CFENCE(); __builtin_amdgcn_s_barrier(); CFENCE();  // all done reading bufs
    Bload((k + 2) * 32, e0, e1);
    Agload(0, (k + 2) * 32);
    // odd: tile k+1 (buf1); write B(k+2) -> Bs[0]; load tile k+3 (o-regs)
    vm_wait<4>();                         // own A(k+1) retired
    CFENCE(); __builtin_amdgcn_s_barrier(); CFENCE();
    compute(1);
    vm_wait<2>();
    Bdswrite(0, e0, e1);
    lgkm0();
    CFENCE(); __builtin_amdgcn_s_barrier(); CFENCE();
    Bload((k + 3) * 32, o0, o1);
    Agload(1, (k + 3) * 32);
  }
  // epilogue: tiles 14, 15
  vm_wait<4>();                           // own A(14) retired
  CFENCE(); __builtin_amdgcn_s_barrier(); CFENCE();
  compute(0);
  vm_wait<0>();                           // B(15) regs + A(15) retired
  Bdswrite(1, o0, o1);
  lgkm0();
  CFENCE(); __builtin_amdgcn_s_barrier(); CFENCE();
  compute(1);

  const int cc = l & 15, r4 = (l >> 4) * 4;
  const int row0 = tm * 128 + wr * 64;
  const int col0 = tn * 128 + wc * 64;
  #pragma unroll
  for (int m = 0; m < 4; ++m) {
    #pragma unroll
    for (int n = 0; n < 4; ++n) {
      const int row = row0 + m * 16 + r4;
      const int col = col0 + n * 16 + cc;
      long long base = (long long)bz * 2097152 + (long long)row * 4096 + col;
      #pragma unroll
      for (int j = 0; j < 4; ++j)
        __builtin_nontemporal_store(acc[m][n][j], &C[base + (long long)j * 4096]);
    }
  }
}

// ---------------------------------------------------------------------------
extern "C" void kernel_launch(void* const* d_in, const int* in_sizes, int n_in,
                              void* d_out, int out_size, void* d_ws, size_t ws_size,
                              hipStream_t stream) {
  (void)in_sizes; (void)n_in; (void)out_size; (void)ws_size;
  const float* x = (const float*)d_in[0];   // [16][512][4096]
  const float* W = (const float*)d_in[1];   // [512][512]
  float* out = (float*)d_out;               // [16][512][4096] = 128 MiB
  char* ws = (char*)d_ws;

  // d_out scratch (dead before final gemm overwrites it):
  unsigned short* P = (unsigned short*)((char*)d_out + 67108864); // [64,84 MiB) bf16 splitK partials
  float* s_stats    = (float*)((char*)d_out + 67108864);          // reuses P space (P dead after reduce_mirror)

  // ws layout (88.5 MiB high water, known-safe):
  unsigned short* x_bf = (unsigned short*)ws;                 // [0, 64 MiB)
  unsigned short* G_bf = (unsigned short*)(ws + 67108864);    // 8 MiB
  float*          s_f  = (float*)(ws + 75497472);             // 16 MiB
  unsigned short* W_bf = (unsigned short*)(ws + 92274688);    // 0.5 MiB
  unsigned short* a_bf = G_bf;   // aliases G_bf (dead after s-gemm)

  // 1) cvt x -> x_bf and W -> W_bf (single streaming launch)
  cvt2_kernel<<<4096, 256, 0, stream>>>(x, x_bf, W, W_bf);

  // 2) G = X X^T: symmetric tiles x 4 K-splits, batch-pinned XCD swizzle
  gemm_gsym<<<640, 256, 0, stream>>>(x_bf, P);

  // 3) reduce partials (fp32 sum), write bf16 G (+ mirrored transpose)
  reduce_mirror<<<dim3(10, 16), 256, 0, stream>>>(P, G_bf);

  // 4) s = G W^T (f32) + per-row LSE partials (row-softmax fused)
  gemm_s<<<dim3(64, 16), 256, 0, stream>>>(G_bf, W_bf, s_f, s_stats);

  // 5) col_softmax_v2: LSE combine + p + col-softmax + identity fold -> a
  col_softmax_v2<<<dim3(16, 16), 256, 0, stream>>>(s_f, s_stats, a_bf);

  // 6) out = (a+I) @ X with fused B-transpose (reads x_bf directly)
  gemm_out<<<dim3(128, 16), 256, 0, stream>>>(a_bf, x_bf, out);
}